// Round 15
// baseline (344.355 us; speedup 1.0000x reference)
//
#include <hip/hip_runtime.h>
#include <cmath>

#define N_NODES 8192
#define N_EDGES 131072
#define NB      256
#define NH      128
#define D3      384
#define D6      768
#define SMM     96   // max nodes per (graph,side)
#define SLD     104  // LDS stride for S (96 + 8 pad)
#define MAXDEG  64   // bucket capacity per dst node; Binomial mean 16, 64 = +12 sigma

typedef __attribute__((ext_vector_type(8))) short short8v;
typedef __attribute__((ext_vector_type(4))) float f32x4;
typedef unsigned short bf16t;

__device__ __forceinline__ float sigf(float x){ return 1.0f/(1.0f+__expf(-x)); }
__device__ __forceinline__ unsigned short f2bf(float x){
  unsigned u = __float_as_uint(x);
  unsigned r = u + 0x7FFF + ((u>>16)&1);   // round-to-nearest-even
  return (unsigned short)(r>>16);
}
__device__ __forceinline__ float bfl(unsigned u){ return __uint_as_float(u<<16); }
__device__ __forceinline__ float bfh(unsigned u){ return __uint_as_float(u & 0xFFFF0000u); }
__device__ __forceinline__ float b2f(bf16t u){ return __uint_as_float(((unsigned)u)<<16); }
// h0[j] from LSTM step-0 collapse (q_star=h=c=0)
__device__ __forceinline__ float h0val(const float* bih, const float* bhh, int j){
  float c = sigf(bih[j]+bhh[j]) * tanhf(bih[2*D6+j]+bhh[2*D6+j]);
  return sigf(bih[3*D6+j]+bhh[3*D6+j]) * tanhf(c);
}

// xw = x @ W via MFMA (device body); x bf16 row stride xs, Wt bf16 [128][K]
// vb in [0,512): side*256+b; 4 waves = 32 rows x 128 cols
__device__ __forceinline__ void xw_body(int vb, int t,
    const bf16t* __restrict__ x1, const bf16t* __restrict__ x2, int xs, int K,
    const bf16t* __restrict__ Wt, bf16t* __restrict__ xw1, bf16t* __restrict__ xw2){
  int side = vb >> 8; int b = vb & 255;
  const bf16t* x = side? x2:x1;
  bf16t* xw = side? xw2:xw1;
  int w = t>>6, lane = t&63;
  int lm = lane&15, quad = lane>>4;
  int r0 = b*32 + (w>>1)*16;
  int c0 = (w&1)*64;
  const bf16t* a = x + (size_t)(r0+lm)*xs + quad*8;
  f32x4 acc[4] = {};
  for (int k=0;k<K;k+=32){
    short8v af = *(const short8v*)(a + k);
    #pragma unroll
    for (int ni=0;ni<4;ni++){
      short8v bf = *(const short8v*)(Wt + (size_t)(c0+ni*16+lm)*K + quad*8 + k);
      acc[ni] = __builtin_amdgcn_mfma_f32_16x16x32_bf16(af, bf, acc[ni], 0,0,0);
    }
  }
  #pragma unroll
  for (int ni=0;ni<4;ni++)
    #pragma unroll
    for (int r=0;r<4;r++){
      int row = r0 + quad*4 + r, col = c0 + ni*16 + lm;
      xw[(size_t)row*NH + col] = f2bf(acc[ni][r]);
    }
}

// ---------- setup ----------

// minimal critical-path setup, branch by block range:
//   [0,1024)     : feats fp32 -> bf16 (both sides)  [needed by k_fill2 xw0]
//   [1024,1027)  : W_l transpose -> bf16            [needed by k_fill2 xw0]
//   [1027,1059)  : init ecur/cnt                    [needed by k_fill2]
__global__ __launch_bounds__(256) void k_setup(
    const float* __restrict__ fe1, const float* __restrict__ fe2,
    short* __restrict__ xf1, short* __restrict__ xf2,
    const float* __restrict__ W0, const float* __restrict__ W1, const float* __restrict__ W2,
    bf16t* __restrict__ Wt,
    int* ecur1, int* ecur2, int* cnt1, int* cnt2){
  int b = blockIdx.x, tid = threadIdx.x;
  if (b < 1024){
    int t = b*256 + tid;
    int side = t >= 131072; int i = t & 131071;
    float4 v = ((const float4*)(side? fe2:fe1))[i];
    short4 o = { (short)f2bf(v.x), (short)f2bf(v.y), (short)f2bf(v.z), (short)f2bf(v.w) };
    ((short4*)(side? xf2:xf1))[i] = o;
  } else if (b < 1027){
    int l = b - 1024;
    const float* W = (l==0)? W0 : ((l==1)? W1 : W2);
    int K = (l==0)? 64 : 128;
    bf16t* dst = Wt + ((l==0)? 0 : ((l==1)? 128*64 : 128*64+128*128));
    for (int idx = tid; idx < 128*K; idx += 256){
      int n = idx / K, k = idx - n*K;
      dst[idx] = f2bf(W[k*NH + n]);
    }
  } else {
    int t = (b-1027)*256 + tid;
    if (t < N_NODES){ ecur1[t]=0; ecur2[t]=0; }
    if (t < NB){ cnt1[t]=0; cnt2[t]=0; }
  }
}

// bucket scatter (blocks 0-1023): es=src, ec=raw ea; + batch-cnt atomics
// || layer-0 xw MFMA (blocks 1024-1535)
__global__ __launch_bounds__(256) void k_fill2(
    const int* __restrict__ ei1, const float* __restrict__ ea1,
    const int* __restrict__ ei2, const float* __restrict__ ea2,
    int* cur1, int* es1, float* ec1, int* cur2, int* es2, float* ec2,
    const int* __restrict__ b1, const int* __restrict__ b2, int* cnt1, int* cnt2,
    const bf16t* __restrict__ xf1, const bf16t* __restrict__ xf2,
    const bf16t* __restrict__ Wt, bf16t* __restrict__ xwA1, bf16t* __restrict__ xwA2){
  int blk = blockIdx.x;
  if (blk < 1024){
    int idx = blk*256 + threadIdx.x;
    int side = idx >= N_EDGES;
    int e = idx & (N_EDGES-1);
    const int* ei = side? ei2:ei1; const float* ea = side? ea2:ea1;
    int* cur = side? cur2:cur1; int* es = side? es2:es1; float* ec = side? ec2:ec1;
    int s = ei[e], d = ei[N_EDGES+e];
    int pos = atomicAdd(&cur[d], 1);
    if (pos < MAXDEG){
      es[d*MAXDEG + pos] = s;
      ec[d*MAXDEG + pos] = ea[e];
    }
    if (idx < N_NODES){ atomicAdd(&cnt1[b1[idx]],1); atomicAdd(&cnt2[b2[idx]],1); }
  } else {
    xw_body(blk-1024, threadIdx.x, xf1, xf2, 64, 64, Wt, xwA1, xwA2);
  }
}

// deg from buckets (blocks 0-63: deg[i] = 1 + sum bucket ea, no atomics)
// + batch-count scans (blocks 64,65)
__global__ __launch_bounds__(256) void k_deg2(
    const int* __restrict__ cur1, const float* __restrict__ ec1, float* deg1,
    const int* __restrict__ cur2, const float* __restrict__ ec2, float* deg2,
    const int* __restrict__ c1, const int* __restrict__ c2, int* st1, int* st2){
  __shared__ int ps[256];
  int blk = blockIdx.x, t = threadIdx.x;
  if (blk < 64){
    int idx = blk*256 + t;
    int side = idx >= N_NODES;
    int i = idx & (N_NODES-1);
    const int* cur = side? cur2:cur1;
    const float* ec = side? ec2:ec1;
    float* deg = side? deg2:deg1;
    int ce = cur[i]; if (ce > MAXDEG) ce = MAXDEG;
    float s = 1.0f;
    const float* p = ec + (size_t)i*MAXDEG;
    for (int k=0;k<ce;k++) s += p[k];
    deg[i] = s;
  } else {
    const int* c = (blk==65)? c2:c1; int* st = (blk==65)? st2:st1;
    ps[t]=c[t]; __syncthreads();
    for (int d=1; d<256; d<<=1){
      int v = (t>=d)? ps[t-d]:0;
      __syncthreads();
      ps[t]+=v;
      __syncthreads();
    }
    st[t+1]=ps[t];
    if (t==0) st[0]=0;
  }
}

// ---------- GCN ----------

// fused gather(l) + xw(l+1), one block per (side, 16-row tile); grid 1024
// coefmode=1 (layer 0): ec holds raw ea; compute coef inline and write back
__global__ __launch_bounds__(256) void k_gxw(
    const bf16t* __restrict__ xwi1, const bf16t* __restrict__ xwi2,
    const int* __restrict__ cur1, const int* __restrict__ cur2,
    const int* __restrict__ es1, const int* __restrict__ es2,
    float* __restrict__ ec1, float* __restrict__ ec2,
    const float* __restrict__ d1, const float* __restrict__ d2,
    const float* __restrict__ bias, int loff, int coefmode,
    bf16t* __restrict__ h1, bf16t* __restrict__ h2,
    const bf16t* __restrict__ Wl,
    bf16t* __restrict__ xwo1, bf16t* __restrict__ xwo2){
  int blk = blockIdx.x;
  int side = blk >> 9; int b = blk & 511;
  const ushort4* xw = (const ushort4*)(side? xwi2:xwi1);
  const int* cur = side? cur2:cur1;
  const int* es  = side? es2:es1;
  float* ec = side? ec2:ec1;
  const float* deg = side? d2:d1;
  bf16t* h = side? h2:h1;
  int t = threadIdx.x;
  int c4 = t & 31;
  float4 bv = ((const float4*)bias)[c4];
  #pragma unroll
  for (int grp=0; grp<2; grp++){
    int i = b*16 + grp*8 + (t>>5);
    float dgi = deg[i];
    float sc = 1.0f/dgi;
    float rsq_d = rsqrtf(dgi);
    ushort4 v = xw[(size_t)i*32 + c4];
    float4 acc = {b2f(v.x)*sc, b2f(v.y)*sc, b2f(v.z)*sc, b2f(v.w)*sc};
    int r = i*MAXDEG;
    int ce = cur[i]; if (ce > MAXDEG) ce = MAXDEG;
    int r1 = r + ce;
    for (; r+3<r1; r+=4){
      int s0=es[r], s1=es[r+1], s2=es[r+2], s3=es[r+3];
      float w0=ec[r], w1=ec[r+1], w2=ec[r+2], w3=ec[r+3];
      if (coefmode){
        w0 *= rsqrtf(deg[s0])*rsq_d;
        w1 *= rsqrtf(deg[s1])*rsq_d;
        w2 *= rsqrtf(deg[s2])*rsq_d;
        w3 *= rsqrtf(deg[s3])*rsq_d;
        if (c4==0){ ec[r]=w0; ec[r+1]=w1; ec[r+2]=w2; ec[r+3]=w3; }
      }
      ushort4 u0 = xw[(size_t)s0*32 + c4];
      ushort4 u1 = xw[(size_t)s1*32 + c4];
      ushort4 u2 = xw[(size_t)s2*32 + c4];
      ushort4 u3 = xw[(size_t)s3*32 + c4];
      acc.x += b2f(u0.x)*w0 + b2f(u1.x)*w1 + b2f(u2.x)*w2 + b2f(u3.x)*w3;
      acc.y += b2f(u0.y)*w0 + b2f(u1.y)*w1 + b2f(u2.y)*w2 + b2f(u3.y)*w3;
      acc.z += b2f(u0.z)*w0 + b2f(u1.z)*w1 + b2f(u2.z)*w2 + b2f(u3.z)*w3;
      acc.w += b2f(u0.w)*w0 + b2f(u1.w)*w1 + b2f(u2.w)*w2 + b2f(u3.w)*w3;
    }
    for (; r<r1; r++){
      int s0=es[r]; float w0=ec[r];
      if (coefmode){
        w0 *= rsqrtf(deg[s0])*rsq_d;
        if (c4==0) ec[r]=w0;
      }
      ushort4 u0 = xw[(size_t)s0*32 + c4];
      acc.x+=b2f(u0.x)*w0; acc.y+=b2f(u0.y)*w0; acc.z+=b2f(u0.z)*w0; acc.w+=b2f(u0.w)*w0;
    }
    acc.x+=bv.x; acc.y+=bv.y; acc.z+=bv.z; acc.w+=bv.w;
    acc.x = (acc.x>0.f)?acc.x:0.2f*acc.x;
    acc.y = (acc.y>0.f)?acc.y:0.2f*acc.y;
    acc.z = (acc.z>0.f)?acc.z:0.2f*acc.z;
    acc.w = (acc.w>0.f)?acc.w:0.2f*acc.w;
    ((ushort4*)(h + (size_t)i*D3 + loff))[c4] =
      make_ushort4(f2bf(acc.x), f2bf(acc.y), f2bf(acc.z), f2bf(acc.w));
  }
  __syncthreads();
  // xw phase: same 16 rows, K=128 from the slice just written
  int w = t>>6, lane = t&63;
  int lm = lane&15, quad = lane>>4;
  const bf16t* x = (side? h2:h1) + loff;
  int r0 = b*16;
  int c0 = w*32;
  const bf16t* a = x + (size_t)(r0+lm)*D3 + quad*8;
  bf16t* xwo = side? xwo2:xwo1;
  f32x4 acc0={0,0,0,0}, acc1={0,0,0,0};
  for (int k=0;k<128;k+=32){
    short8v af = *(const short8v*)(a + k);
    short8v b0 = *(const short8v*)(Wl + (size_t)(c0+lm)*128 + quad*8 + k);
    short8v b1 = *(const short8v*)(Wl + (size_t)(c0+16+lm)*128 + quad*8 + k);
    acc0 = __builtin_amdgcn_mfma_f32_16x16x32_bf16(af, b0, acc0, 0,0,0);
    acc1 = __builtin_amdgcn_mfma_f32_16x16x32_bf16(af, b1, acc1, 0,0,0);
  }
  #pragma unroll
  for (int r=0;r<4;r++){
    int row = r0 + quad*4 + r;
    xwo[(size_t)row*NH + c0 + lm]      = f2bf(acc0[r]);
    xwo[(size_t)row*NH + c0 + 16 + lm] = f2bf(acc1[r]);
  }
}

// fused self-loop + bucket gather + bias + leaky; layer 2 fuses l2norm -> f bf16
// + co-dispatched late-setup (full occupancy: only 3KB LDS):
//   blocks [0,2048)     : gather (l2mode)
//   blocks [2048,4352)  : Wih right half -> bf16 [3072][768]   (consumed by k_gates)
//   blocks [4352,5120)  : Wp1 fp32 -> bf16                     (consumed by p1)
//   blocks [5120,5888)  : cvec (4 waves/block, h0 in LDS)      (consumed by k_gates)
__global__ __launch_bounds__(256) void k_gather(const bf16t* __restrict__ xw1, const bf16t* __restrict__ xw2,
                                                const int* __restrict__ cur1, const int* __restrict__ cur2,
                                                const int* __restrict__ es1, const int* __restrict__ es2,
                                                const float* __restrict__ ec1, const float* __restrict__ ec2,
                                                const float* __restrict__ d1, const float* __restrict__ d2,
                                                const float* __restrict__ b,
                                                bf16t* __restrict__ h1, bf16t* __restrict__ h2, int loff,
                                                int l2mode, bf16t* __restrict__ f1, bf16t* __restrict__ f2,
                                                const float* __restrict__ Wih, short* __restrict__ Wih16,
                                                const float* __restrict__ Wp1, short* __restrict__ Wp116,
                                                const float* __restrict__ Whh,
                                                const float* __restrict__ bih, const float* __restrict__ bhh,
                                                float* __restrict__ cvec){
  __shared__ float hs_cv[D6];
  int blk = blockIdx.x;
  int t = threadIdx.x;
  if (blk >= 2048){
    if (blk < 4352){
      int tt = (blk-2048)*256 + t;
      int n = tt/192, q = tt - n*192;
      float4 v = ((const float4*)(Wih + (size_t)n*1536 + 768))[q];
      short4 o = { (short)f2bf(v.x), (short)f2bf(v.y), (short)f2bf(v.z), (short)f2bf(v.w) };
      ((short4*)Wih16)[tt] = o;
    } else if (blk < 5120){
      int tt = (blk-4352)*256 + t;
      float4 v = ((const float4*)Wp1)[tt];
      short4 o = { (short)f2bf(v.x), (short)f2bf(v.y), (short)f2bf(v.z), (short)f2bf(v.w) };
      ((short4*)Wp116)[tt] = o;
    } else {
      int j0 = (blk - 5120)*4;
      for (int k=t; k<D6; k+=256) hs_cv[k] = h0val(bih,bhh,k);
      __syncthreads();
      int w = t>>6, lane = t&63;
      int j = j0 + w;
      const float4* wi = (const float4*)(Wih + (size_t)j*(2*D6));
      const float4* wh = (const float4*)(Whh + (size_t)j*D6);
      const float4* h4 = (const float4*)hs_cv;
      float acc=0;
      #pragma unroll
      for (int m=0;m<3;m++){
        float4 hv = h4[m*64+lane];
        float4 a = wi[m*64+lane];
        float4 bb = wh[m*64+lane];
        acc += hv.x*(a.x+bb.x) + hv.y*(a.y+bb.y) + hv.z*(a.z+bb.z) + hv.w*(a.w+bb.w);
      }
      #pragma unroll
      for (int m=1;m<64;m<<=1) acc += __shfl_xor(acc,m,64);
      if (lane==0) cvec[j]=acc+bih[j]+bhh[j];
    }
    return;
  }
  int side = blk >> 10; int bb = blk & 1023;
  const ushort4* xw = (const ushort4*)(side? xw2:xw1);
  const int* cur = side? cur2:cur1;
  const int* es  = side? es2:es1;
  const float* ec= side? ec2:ec1;
  const float* deg = side? d2:d1;
  bf16t* h = side? h2:h1;
  int i = bb*8 + (t>>5);
  int c4 = t & 31;
  float sc = 1.0f/deg[i];
  ushort4 v = xw[(size_t)i*32 + c4];
  float4 acc = {b2f(v.x)*sc, b2f(v.y)*sc, b2f(v.z)*sc, b2f(v.w)*sc};
  int r = i*MAXDEG;
  int ce = cur[i]; if (ce > MAXDEG) ce = MAXDEG;
  int r1 = r + ce;
  for (; r+3<r1; r+=4){
    int s0=es[r], s1=es[r+1], s2=es[r+2], s3=es[r+3];
    float w0=ec[r], w1=ec[r+1], w2=ec[r+2], w3=ec[r+3];
    ushort4 u0 = xw[(size_t)s0*32 + c4];
    ushort4 u1 = xw[(size_t)s1*32 + c4];
    ushort4 u2 = xw[(size_t)s2*32 + c4];
    ushort4 u3 = xw[(size_t)s3*32 + c4];
    acc.x += b2f(u0.x)*w0 + b2f(u1.x)*w1 + b2f(u2.x)*w2 + b2f(u3.x)*w3;
    acc.y += b2f(u0.y)*w0 + b2f(u1.y)*w1 + b2f(u2.y)*w2 + b2f(u3.y)*w3;
    acc.z += b2f(u0.z)*w0 + b2f(u1.z)*w1 + b2f(u2.z)*w2 + b2f(u3.z)*w3;
    acc.w += b2f(u0.w)*w0 + b2f(u1.w)*w1 + b2f(u2.w)*w2 + b2f(u3.w)*w3;
  }
  for (; r<r1; r++){
    int s0=es[r]; float w0=ec[r];
    ushort4 u0 = xw[(size_t)s0*32 + c4];
    acc.x+=b2f(u0.x)*w0; acc.y+=b2f(u0.y)*w0; acc.z+=b2f(u0.z)*w0; acc.w+=b2f(u0.w)*w0;
  }
  float4 bv = ((const float4*)b)[c4];
  acc.x+=bv.x; acc.y+=bv.y; acc.z+=bv.z; acc.w+=bv.w;
  acc.x = (acc.x>0.f)?acc.x:0.2f*acc.x;
  acc.y = (acc.y>0.f)?acc.y:0.2f*acc.y;
  acc.z = (acc.z>0.f)?acc.z:0.2f*acc.z;
  acc.w = (acc.w>0.f)?acc.w:0.2f*acc.w;
  if (!l2mode){
    ((ushort4*)(h + (size_t)i*D3 + loff))[c4] =
      make_ushort4(f2bf(acc.x), f2bf(acc.y), f2bf(acc.z), f2bf(acc.w));
  } else {
    ushort4 u0 = ((const ushort4*)(h + (size_t)i*D3))[c4];
    ushort4 u1 = ((const ushort4*)(h + (size_t)i*D3 + 128))[c4];
    float4 v0 = {b2f(u0.x), b2f(u0.y), b2f(u0.z), b2f(u0.w)};
    float4 v1 = {b2f(u1.x), b2f(u1.y), b2f(u1.z), b2f(u1.w)};
    float ss = v0.x*v0.x+v0.y*v0.y+v0.z*v0.z+v0.w*v0.w
             + v1.x*v1.x+v1.y*v1.y+v1.z*v1.z+v1.w*v1.w
             + acc.x*acc.x+acc.y*acc.y+acc.z*acc.z+acc.w*acc.w;
    #pragma unroll
    for (int m=1;m<32;m<<=1) ss += __shfl_xor(ss, m, 64);   // 32-lane node group
    float scale = 1.0f/fmaxf(sqrtf(ss), 1e-12f);
    bf16t* f = side? f2:f1;
    ((ushort4*)(f + (size_t)i*D6))[c4]       = make_ushort4(f2bf(v0.x*scale),f2bf(v0.y*scale),f2bf(v0.z*scale),f2bf(v0.w*scale));
    ((ushort4*)(f + (size_t)i*D6 + 128))[c4] = make_ushort4(f2bf(v1.x*scale),f2bf(v1.y*scale),f2bf(v1.z*scale),f2bf(v1.w*scale));
    ((ushort4*)(f + (size_t)i*D6 + 256))[c4] = make_ushort4(f2bf(acc.x*scale),f2bf(acc.y*scale),f2bf(acc.z*scale),f2bf(acc.w*scale));
  }
}

// ---------- interaction fused + step-1 attention tail, one block per (graph,side) ----------
// phase A: S tiles via MFMA into LDS (19.9KB LDS -> 8 blocks/CU)
// phase B: dst[row][0:384] = sum_j S[row][j]*src[j][0:384] as a weighted row-gather
//          (uint loads = 2 bf16/lane x 3 iters = 384 ch; S coef is wave-uniform broadcast)
__global__ __launch_bounds__(256) void k_inter(bf16t* __restrict__ f1, bf16t* __restrict__ f2,
                                               const int* __restrict__ st1, const int* __restrict__ st2,
                                               const float* __restrict__ bih, const float* __restrict__ bhh,
                                               bf16t* __restrict__ Ab){
  __shared__ __align__(16) bf16t Sld[SMM*SLD];   // 19968 B; re-aliased by attention tail
  int bx = blockIdx.x;
  int t = threadIdx.x;
  int side = bx >> 8, g = bx & (NB-1);
  int i0 = st1[g]; int n1 = st1[g+1]-i0; if (n1>SMM) n1=SMM;
  int j0 = st2[g]; int n2 = st2[g+1]-j0; if (n2>SMM) n2=SMM;
  int cnt = side? n2 : n1;
  int J   = side? n1 : n2;
  int r0base = side? j0 : i0;
  int c0base = side? i0 : j0;
  const bf16t* rowp = (side? f2 : f1);
  const bf16t* colp = (side? f1 : f2);
  const bf16t* src = colp + (size_t)c0base*D6;
  bf16t* dst = (side? f2 : f1) + (size_t)r0base*D6 + D3;
  int w = t>>6, lane = t&63;
  int lm = lane & 15, quad = lane >> 4;
  // phase A: S tiles via MFMA into LDS (write-mask covers all phase-B reads: j < J, row < cnt)
  int nti = (cnt+15)>>4, ntj = (J+15)>>4;
  for (int tile = w; tile < nti*ntj; tile += 4){
    int ti = tile/ntj, tj = tile - ti*ntj;
    int ar = r0base + ti*16 + lm; if (ar > N_NODES-1) ar = N_NODES-1;
    int br = c0base + tj*16 + lm; if (br > N_NODES-1) br = N_NODES-1;
    const bf16t* a = rowp + (size_t)ar*D6 + quad*8;
    const bf16t* b = colp + (size_t)br*D6 + quad*8;
    f32x4 acc = {0,0,0,0};
    #pragma unroll
    for (int k=0; k<384; k+=32){
      short8v af = *(const short8v*)(a + k);
      short8v bf = *(const short8v*)(b + k);
      acc = __builtin_amdgcn_mfma_f32_16x16x32_bf16(af, bf, acc, 0, 0, 0);
    }
    int col = tj*16 + lm;
    #pragma unroll
    for (int r=0;r<4;r++){
      int row = ti*16 + quad*4 + r;
      if (row < cnt && col < J)
        Sld[row*SLD + col] = f2bf(acc[r]);
    }
  }
  __syncthreads();
  // phase B: weighted row-gather over the FIRST 384 channels of src, one row per wave
  for (int row = w; row < cnt; row += 4){
    float acc[6] = {};
    const bf16t* sr = Sld + row*SLD;
    for (int j = 0; j < J; j++){
      float s = b2f(sr[j]);
      const uint* xr = (const uint*)(src + (size_t)j*D6);
      #pragma unroll
      for (int m=0;m<3;m++){
        uint rv = xr[m*64+lane];
        acc[m*2+0] += s*bfl(rv);
        acc[m*2+1] += s*bfh(rv);
      }
    }
    #pragma unroll
    for (int m=0;m<3;m++)
      ((ushort2*)(dst + (size_t)row*D6 + m*128))[lane] =
        make_ushort2(f2bf(acc[m*2]), f2bf(acc[m*2+1]));
  }
  // ---- step-1 attention tail for this (g,side); Sld re-aliased as hs/e_s/part ----
  __syncthreads();
  {
    float4* hs = (float4*)Sld;                 // 192 float4 = 3072 B
    float* e_s = ((float*)Sld) + 768;          // 96 floats
    float* part = ((float*)Sld) + 864;         // 4*768 floats
    const bf16t* x = rowp + (size_t)r0base*D6;
    if (t<192){
      int j = t*4;
      hs[t] = make_float4(h0val(bih,bhh,j), h0val(bih,bhh,j+1), h0val(bih,bhh,j+2), h0val(bih,bhh,j+3));
    }
    __syncthreads();
    for (int n=w; n<cnt; n+=4){
      const uint2* xr = (const uint2*)(x + (size_t)n*D6);
      float p = 0;
      #pragma unroll
      for (int m=0;m<3;m++){
        uint2 rv = xr[m*64+lane];
        float4 hvv = hs[m*64+lane];
        p += bfl(rv.x)*hvv.x + bfh(rv.x)*hvv.y + bfl(rv.y)*hvv.z + bfh(rv.y)*hvv.w;
      }
      #pragma unroll
      for (int m=1;m<64;m<<=1) p += __shfl_xor(p,m,64);
      if (lane==0) e_s[n]=p;
    }
    __syncthreads();
    if (w==0){
      float mx=-INFINITY;
      for (int n=lane;n<cnt;n+=64) mx=fmaxf(mx,e_s[n]);
      #pragma unroll
      for (int m=1;m<64;m<<=1) mx=fmaxf(mx,__shfl_xor(mx,m,64));
      float s=0;
      for (int n=lane;n<cnt;n+=64) s+=__expf(e_s[n]-mx);
      #pragma unroll
      for (int m=1;m<64;m<<=1) s+=__shfl_xor(s,m,64);
      float inv=1.0f/s;
      for (int n=lane;n<cnt;n+=64) e_s[n]=__expf(e_s[n]-mx)*inv;
    }
    __syncthreads();
    float av[3][4] = {};
    for (int n=w; n<cnt; n+=4){
      float a = e_s[n];
      const uint2* xr = (const uint2*)(x + (size_t)n*D6);
      #pragma unroll
      for (int m=0;m<3;m++){
        uint2 rv = xr[m*64+lane];
        av[m][0]+=a*bfl(rv.x); av[m][1]+=a*bfh(rv.x); av[m][2]+=a*bfl(rv.y); av[m][3]+=a*bfh(rv.y);
      }
    }
    #pragma unroll
    for (int m=0;m<3;m++)
      *(float4*)&part[w*D6 + (m*64+lane)*4] = make_float4(av[m][0],av[m][1],av[m][2],av[m][3]);
    __syncthreads();
    if (t<192){
      float4 p0 = *(const float4*)&part[0*D6 + t*4];
      float4 p1 = *(const float4*)&part[1*D6 + t*4];
      float4 p2 = *(const float4*)&part[2*D6 + t*4];
      float4 p3 = *(const float4*)&part[3*D6 + t*4];
      float4 s = make_float4(p0.x+p1.x+p2.x+p3.x, p0.y+p1.y+p2.y+p3.y,
                             p0.z+p1.z+p2.z+p3.z, p0.w+p1.w+p2.w+p3.w);
      ushort4 o = make_ushort4(f2bf(s.x), f2bf(s.y), f2bf(s.z), f2bf(s.w));
      ((ushort4*)(Ab + (size_t)(side*NB+g)*D6))[t]=o;
    }
  }
}

// ---------- set2set ----------

// fused attention: e=x.hv, segment softmax, r=sum a*x (wave-parallel); x bf16; r bf16
__global__ __launch_bounds__(256) void k_att(const bf16t* __restrict__ f1, const bf16t* __restrict__ f2,
                                             const float* __restrict__ hbase, int perseg,
                                             const float* __restrict__ bih, const float* __restrict__ bhh,
                                             const int* __restrict__ st1, const int* __restrict__ st2,
                                             bf16t* __restrict__ dst16, long sidestep, long dstride){
  __shared__ float4 hs[192];
  __shared__ float e_s[SMM];
  __shared__ float part[4][D6];
  int side = blockIdx.x >> 8, g = blockIdx.x & (NB-1);
  const int* st = side? st2:st1;
  int n0 = st[g]; int cnt = st[g+1]-n0; if (cnt>SMM) cnt=SMM;
  const bf16t* x = (side? f2:f1) + (size_t)n0*D6;
  int t = threadIdx.x, w = t>>6, lane = t&63;
  if (t<192){
    if (perseg){
      hs[t] = ((const float4*)(hbase + (size_t)(side*NB+g)*D6))[t];
    } else {
      int j = t*4;
      hs[t] = make_float4(h0val(bih,bhh,j), h0val(bih,bhh,j+1), h0val(bih,bhh,j+2), h0val(bih,bhh,j+3));
    }
  }
  __syncthreads();
  for (int n=w; n<cnt; n+=4){
    const uint2* xr = (const uint2*)(x + (size_t)n*D6);
    float p = 0;
    #pragma unroll
    for (int m=0;m<3;m++){
      uint2 rv = xr[m*64+lane];
      float4 hvv = hs[m*64+lane];
      p += bfl(rv.x)*hvv.x + bfh(rv.x)*hvv.y + bfl(rv.y)*hvv.z + bfh(rv.y)*hvv.w;
    }
    #pragma unroll
    for (int m=1;m<64;m<<=1) p += __shfl_xor(p,m,64);
    if (lane==0) e_s[n]=p;
  }
  __syncthreads();
  if (w==0){
    float mx=-INFINITY;
    for (int n=lane;n<cnt;n+=64) mx=fmaxf(mx,e_s[n]);
    #pragma unroll
    for (int m=1;m<64;m<<=1) mx=fmaxf(mx,__shfl_xor(mx,m,64));
    float s=0;
    for (int n=lane;n<cnt;n+=64) s+=__expf(e_s[n]-mx);
    #pragma unroll
    for (int m=1;m<64;m<<=1) s+=__shfl_xor(s,m,64);
    float inv=1.0f/s;
    for (int n=lane;n<cnt;n+=64) e_s[n]=__expf(e_s[n]-mx)*inv;
  }
  __syncthreads();
  float av[3][4] = {};
  for (int n=w; n<cnt; n+=4){
    float a = e_s[n];
    const uint2* xr = (const uint2*)(x + (size_t)n*D6);
    #pragma unroll
    for (int m=0;m<3;m++){
      uint2 rv = xr[m*64+lane];
      av[m][0]+=a*bfl(rv.x); av[m][1]+=a*bfh(rv.x); av[m][2]+=a*bfl(rv.y); av[m][3]+=a*bfh(rv.y);
    }
  }
  #pragma unroll
  for (int m=0;m<3;m++)
    *(float4*)&part[w][(m*64+lane)*4] = make_float4(av[m][0],av[m][1],av[m][2],av[m][3]);
  __syncthreads();
  if (t<192){
    float4 p0 = *(const float4*)&part[0][t*4];
    float4 p1 = *(const float4*)&part[1][t*4];
    float4 p2 = *(const float4*)&part[2][t*4];
    float4 p3 = *(const float4*)&part[3][t*4];
    float4 s = make_float4(p0.x+p1.x+p2.x+p3.x, p0.y+p1.y+p2.y+p3.y,
                           p0.z+p1.z+p2.z+p3.z, p0.w+p1.w+p2.w+p3.w);
    ushort4 o = make_ushort4(f2bf(s.x), f2bf(s.y), f2bf(s.z), f2bf(s.w));
    ushort4* dp = (ushort4*)(dst16 + side*sidestep + (size_t)g*dstride);
    dp[t]=o;
  }
}

// fused gates GEMM + LSTM step-1 pointwise: wave w computes gate w for (16m x 64j) tile
__global__ __launch_bounds__(256) void k_gates(const short* __restrict__ A16,
                                               const short* __restrict__ B16,
                                               const float* __restrict__ cvec,
                                               const float* __restrict__ bih, const float* __restrict__ bhh,
                                               float* __restrict__ h1s, bf16t* __restrict__ z16){
  __shared__ float gbuf[4][16][66];
  int w = threadIdx.x >> 6, lane = threadIdx.x & 63;
  int lm = lane & 15, quad = lane >> 4;
  int bm = blockIdx.x * 16;
  int jb = blockIdx.y * 64;
  const short* a = A16 + (size_t)(bm + lm)*768 + quad*8;
  const short* b = B16 + (size_t)(w*768 + jb + lm)*768 + quad*8;
  f32x4 acc0={0,0,0,0}, acc1={0,0,0,0}, acc2={0,0,0,0}, acc3={0,0,0,0};
  for (int k=0; k<768; k+=32){
    short8v af = *(const short8v*)(a + k);
    short8v b0 = *(const short8v*)(b + k);
    short8v b1 = *(const short8v*)(b + 16*768 + k);
    short8v b2 = *(const short8v*)(b + 32*768 + k);
    short8v b3 = *(const short8v*)(b + 48*768 + k);
    acc0 = __builtin_amdgcn_mfma_f32_16x16x32_bf16(af, b0, acc0, 0, 0, 0);
    acc1 = __builtin_amdgcn_mfma_f32_16x16x32_bf16(af, b1, acc1, 0, 0, 0);
    acc2 = __builtin_amdgcn_mfma_f32_16x16x32_bf16(af, b2, acc2, 0, 0, 0);
    acc3 = __builtin_amdgcn_mfma_f32_16x16x32_bf16(af, b3, acc3, 0, 0, 0);
  }
  #pragma unroll
  for (int r=0;r<4;r++){
    gbuf[w][quad*4+r][lm]      = acc0[r];
    gbuf[w][quad*4+r][16+lm]   = acc1[r];
    gbuf[w][quad*4+r][32+lm]   = acc2[r];
    gbuf[w][quad*4+r][48+lm]   = acc3[r];
  }
  __syncthreads();
  int t = threadIdx.x;
  #pragma unroll
  for (int u=0; u<4; u++){
    int p = t + u*256;
    int mm = p>>6, jj = p&63;
    int j = jb + jj, m = bm + mm;
    float g4[4];
    #pragma unroll
    for (int q=0;q<4;q++) g4[q] = gbuf[q][mm][jj] + cvec[q*D6 + j];
    float c0j = sigf(bih[j]+bhh[j]) * tanhf(bih[2*D6+j]+bhh[2*D6+j]);
    float c = sigf(g4[1])*c0j + sigf(g4[0])*tanhf(g4[2]);
    float h = sigf(g4[3])*tanhf(c);
    h1s[(size_t)m*D6 + j] = h;
    int side = m>>8, g = m&255;
    z16[(size_t)g*3072 + side*1536 + j] = f2bf(h);
  }
}

// p1 GEMM via MFMA, split-K=16: pout[z][256x256]
__global__ __launch_bounds__(256) void k_gemm_mfma_p1(const short* __restrict__ A16,
                                                      const short* __restrict__ B16,
                                                      float* __restrict__ pout){
  int w = threadIdx.x >> 6, lane = threadIdx.x & 63;
  int lm = lane & 15, quad = lane >> 4;
  int bm = blockIdx.x * 16;
  int bn = w * 64;
  int kbase = blockIdx.y * 192;
  const short* a = A16 + (size_t)(bm + lm)*3072 + quad*8 + kbase;
  const short* b = B16 + (size_t)(bn + lm)*3072 + quad*8 + kbase;
  f32x4 acc0={0,0,0,0}, acc1={0,0,0,0}, acc2={0,0,0,0}, acc3={0,0,0,0};
  for (int k=0; k<192; k+=32){
    short8v af = *(const short8v*)(a + k);
    short8v b0 = *(const short8v*)(b + k);
    short8v b1 = *(const short8v*)(b + 16*3072 + k);
    short8v b2 = *(const short8v*)(b + 32*3072 + k);
    short8v b3 = *(const short8v*)(b + 48*3072 + k);
    acc0 = __builtin_amdgcn_mfma_f32_16x16x32_bf16(af, b0, acc0, 0, 0, 0);
    acc1 = __builtin_amdgcn_mfma_f32_16x16x32_bf16(af, b1, acc1, 0, 0, 0);
    acc2 = __builtin_amdgcn_mfma_f32_16x16x32_bf16(af, b2, acc2, 0, 0, 0);
    acc3 = __builtin_amdgcn_mfma_f32_16x16x32_bf16(af, b3, acc3, 0, 0, 0);
  }
  float* po = pout + (size_t)blockIdx.y*256*256;
  #pragma unroll
  for (int r=0;r<4;r++){
    size_t base = (size_t)(bm + quad*4 + r)*256 + bn + lm;
    po[base]      = acc0[r];
    po[base + 16] = acc1[r];
    po[base + 32] = acc2[r];
    po[base + 48] = acc3[r];
  }
}

// fused p1-reduce + p2 + p3: block per batch row
__global__ __launch_bounds__(128) void k_p23(const float* __restrict__ pbuf, const float* __restrict__ bp1,
                                             const float* __restrict__ Wp2, const float* __restrict__ bp2,
                                             const float* __restrict__ Wp3, const float* __restrict__ bp3,
                                             float* __restrict__ out){
  __shared__ float zr[256];
  __shared__ float ws[2];
  int m = blockIdx.x, t = threadIdx.x;
  float2 zacc = ((const float2*)(bp1))[t];
  #pragma unroll
  for (int p=0;p<16;p++){
    float2 v = ((const float2*)(pbuf + (size_t)p*256*256 + (size_t)m*256))[t];
    zacc.x += v.x; zacc.y += v.y;
  }
  zr[2*t]   = fmaxf(zacc.x, 0.f);
  zr[2*t+1] = fmaxf(zacc.y, 0.f);
  __syncthreads();
  const float4* wrow = (const float4*)(Wp2 + (size_t)t*256);
  const float4* z4 = (const float4*)zr;
  float acc = bp2[t];
  #pragma unroll 8
  for (int k=0;k<64;k++){
    float4 wv = wrow[k], zv = z4[k];
    acc += wv.x*zv.x + wv.y*zv.y + wv.z*zv.z + wv.w*zv.w;
  }
  float p = fmaxf(acc,0.f)*Wp3[t];
  #pragma unroll
  for (int o=32;o;o>>=1) p += __shfl_down(p,o,64);
  if ((t&63)==0) ws[t>>6]=p;
  __syncthreads();
  if (t==0){ float v=ws[0]+ws[1]+bp3[0]; out[m]=1.0f/(1.0f+__expf(-v)); }
}

// ---------- launch ----------

extern "C" void kernel_launch(void* const* d_in, const int* in_sizes, int n_in,
                              void* d_out, int out_size, void* d_ws, size_t ws_size,
                              hipStream_t stream){
  const float* feat1=(const float*)d_in[0];
  const float* feat2=(const float*)d_in[1];
  const float* ea1  =(const float*)d_in[2];
  const float* ea2  =(const float*)d_in[3];
  const float* W0=(const float*)d_in[4];  const float* b0=(const float*)d_in[5];
  const float* W1=(const float*)d_in[6];  const float* b1=(const float*)d_in[7];
  const float* W2=(const float*)d_in[8];  const float* b2=(const float*)d_in[9];
  const float* Wih=(const float*)d_in[10]; const float* bih=(const float*)d_in[11];
  const float* Whh=(const float*)d_in[12]; const float* bhh=(const float*)d_in[13];
  const float* Wp1=(const float*)d_in[14]; const float* bp1=(const float*)d_in[15];
  const float* Wp2=(const float*)d_in[16]; const float* bp2=(const float*)d_in[17];
  const float* Wp3=(const float*)d_in[18]; const float* bp3=(const float*)d_in[19];
  const int* ei1=(const int*)d_in[20]; const int* ei2=(const int*)d_in[21];
  const int* batch1=(const int*)d_in[22]; const int* batch2=(const int*)d_in[23];
  float* out = (float*)d_out;

  float* base = (float*)d_ws;
  size_t off = 0;
  auto alloc = [&](size_t n)->float* { float* r = base + off; off += (n + 255) & ~(size_t)255; return r; };
  float* deg1 = alloc(N_NODES);          float* deg2 = alloc(N_NODES);
  bf16t* xwA1 = (bf16t*)alloc((size_t)N_NODES*NH/2);
  bf16t* xwA2 = (bf16t*)alloc((size_t)N_NODES*NH/2);
  bf16t* xwB1 = (bf16t*)alloc((size_t)N_NODES*NH/2);
  bf16t* xwB2 = (bf16t*)alloc((size_t)N_NODES*NH/2);
  bf16t* hb1  = (bf16t*)alloc((size_t)N_NODES*D3/2);
  bf16t* hb2  = (bf16t*)alloc((size_t)N_NODES*D3/2);
  bf16t* xf1  = (bf16t*)alloc((size_t)N_NODES*64/2);
  bf16t* xf2  = (bf16t*)alloc((size_t)N_NODES*64/2);
  bf16t* Wtb  = (bf16t*)alloc((size_t)(128*64 + 2*128*128)/2);
  bf16t* f1   = (bf16t*)alloc((size_t)N_NODES*D6/2);
  bf16t* f2   = (bf16t*)alloc((size_t)N_NODES*D6/2);
  float* ecoef1 = alloc((size_t)N_NODES*MAXDEG);  float* ecoef2 = alloc((size_t)N_NODES*MAXDEG);
  float* cvec = alloc(4*D6);
  float* h1s  = alloc((size_t)512*D6);
  bf16t* zbuf16 = (bf16t*)alloc((size_t)256*3072/2);
  float* pbuf = alloc((size_t)16*256*256);
  short* Abuf16 = (short*)alloc((size_t)512*D6/2);
  short* Wih16  = (short*)alloc((size_t)3072*D6/2);
  short* Wp116  = (short*)alloc((size_t)256*3072/2);
  int* cnt1 = (int*)alloc(NB);   int* cnt2 = (int*)alloc(NB);
  int* st1  = (int*)alloc(NB+1); int* st2  = (int*)alloc(NB+1);
  int* ecur1= (int*)alloc(N_NODES); int* ecur2 = (int*)alloc(N_NODES);
  int* esrc1= (int*)alloc((size_t)N_NODES*MAXDEG); int* esrc2 = (int*)alloc((size_t)N_NODES*MAXDEG);
  (void)ws_size; (void)in_sizes; (void)n_in; (void)out_size;

  // minimal setup; bucket scatter||xw0; deg-from-buckets + scans
  k_setup  <<<1059,256,0,stream>>>(feat1,feat2,(short*)xf1,(short*)xf2,
                                   W0,W1,W2,Wtb, ecur1,ecur2,cnt1,cnt2);
  k_fill2  <<<1536,256,0,stream>>>(ei1,ea1, ei2,ea2,
                                   ecur1,esrc1,ecoef1, ecur2,esrc2,ecoef2,
                                   batch1,batch2,cnt1,cnt2,
                                   xf1,xf2,Wtb,xwA1,xwA2);
  k_deg2   <<<66,256,0,stream>>>(ecur1,ecoef1,deg1, ecur2,ecoef2,deg2,
                                 cnt1,cnt2,st1,st2);

  const bf16t* Wt1 = Wtb + 128*64;
  const bf16t* Wt2 = Wtb + 128*64 + 128*128;
  // gather0 (coef inline + write-back) + xw1
  k_gxw<<<1024,256,0,stream>>>(xwA1,xwA2, ecur1,ecur2, esrc1,esrc2, ecoef1,ecoef2,
                               deg1,deg2, b0, 0, 1, hb1,hb2, Wt1, xwB1,xwB2);
  // gather1 + xw2
  k_gxw<<<1024,256,0,stream>>>(xwB1,xwB2, ecur1,ecur2, esrc1,esrc2, ecoef1,ecoef2,
                               deg1,deg2, b1, NH, 0, hb1,hb2, Wt2, xwA1,xwA2);
  // gather2 (l2norm -> f) || Wih16/Wp116 converts || cvec (full occupancy here)
  k_gather <<<5888,256,0,stream>>>(xwA1,xwA2,ecur1,ecur2,esrc1,esrc2,ecoef1,ecoef2,
                                   deg1,deg2,b2,hb1,hb2,2*NH,1,f1,f2,
                                   Wih,(short*)Wih16, Wp1,(short*)Wp116,
                                   Whh,bih,bhh,cvec);

  // fused interaction: per-(graph,side) S via MFMA + weighted-gather apply + att tail
  k_inter <<<512,256,0,stream>>>(f1,f2,st1,st2,bih,bhh,(bf16t*)Abuf16);

  // fused gates GEMM + LSTM step-1 pointwise
  k_gates<<<dim3(32,12),256,0,stream>>>(Abuf16, Wih16, cvec, bih, bhh, h1s, zbuf16);

  // step-2 attention (per-segment h) -> zbuf16 r-slots
  k_att<<<512,256,0,stream>>>(f1,f2,h1s,1,bih,bhh,st1,st2,
                              zbuf16+768,(long)1536,(long)3072);

  // MLP: p1 via MFMA (split-K=16); fused reduce+p2+p3
  k_gemm_mfma_p1<<<dim3(16,16),256,0,stream>>>((const short*)zbuf16, Wp116, pbuf);
  k_p23 <<<256,128,0,stream>>>(pbuf, bp1, Wp2, bp2, Wp3, bp3, out);
}

// Round 17
// 328.572 us; speedup vs baseline: 1.0480x; 1.0480x over previous
//
#include <hip/hip_runtime.h>
#include <cmath>

#define N_NODES 8192
#define N_EDGES 131072
#define NB      256
#define NH      128
#define D3      384
#define D6      768
#define SMM     96   // max nodes per (graph,side)
#define SLD     104  // LDS stride for S (96 + 8 pad)
#define MAXDEG  64   // bucket capacity per dst node; Binomial mean 16, 64 = +12 sigma

typedef __attribute__((ext_vector_type(8))) short short8v;
typedef __attribute__((ext_vector_type(4))) float f32x4;
typedef unsigned short bf16t;

__device__ __forceinline__ float sigf(float x){ return 1.0f/(1.0f+__expf(-x)); }
__device__ __forceinline__ unsigned short f2bf(float x){
  unsigned u = __float_as_uint(x);
  unsigned r = u + 0x7FFF + ((u>>16)&1);   // round-to-nearest-even
  return (unsigned short)(r>>16);
}
__device__ __forceinline__ float bfl(unsigned u){ return __uint_as_float(u<<16); }
__device__ __forceinline__ float bfh(unsigned u){ return __uint_as_float(u & 0xFFFF0000u); }
__device__ __forceinline__ float b2f(bf16t u){ return __uint_as_float(((unsigned)u)<<16); }
// h0[j] from LSTM step-0 collapse (q_star=h=c=0)
__device__ __forceinline__ float h0val(const float* bih, const float* bhh, int j){
  float c = sigf(bih[j]+bhh[j]) * tanhf(bih[2*D6+j]+bhh[2*D6+j]);
  return sigf(bih[3*D6+j]+bhh[3*D6+j]) * tanhf(c);
}

// xw = x @ W via MFMA (device body); x bf16 row stride xs, Wt bf16 [128][K]
// vb in [0,512): side*256+b; 4 waves = 32 rows x 128 cols
__device__ __forceinline__ void xw_body(int vb, int t,
    const bf16t* __restrict__ x1, const bf16t* __restrict__ x2, int xs, int K,
    const bf16t* __restrict__ Wt, bf16t* __restrict__ xw1, bf16t* __restrict__ xw2){
  int side = vb >> 8; int b = vb & 255;
  const bf16t* x = side? x2:x1;
  bf16t* xw = side? xw2:xw1;
  int w = t>>6, lane = t&63;
  int lm = lane&15, quad = lane>>4;
  int r0 = b*32 + (w>>1)*16;
  int c0 = (w&1)*64;
  const bf16t* a = x + (size_t)(r0+lm)*xs + quad*8;
  f32x4 acc[4] = {};
  for (int k=0;k<K;k+=32){
    short8v af = *(const short8v*)(a + k);
    #pragma unroll
    for (int ni=0;ni<4;ni++){
      short8v bf = *(const short8v*)(Wt + (size_t)(c0+ni*16+lm)*K + quad*8 + k);
      acc[ni] = __builtin_amdgcn_mfma_f32_16x16x32_bf16(af, bf, acc[ni], 0,0,0);
    }
  }
  #pragma unroll
  for (int ni=0;ni<4;ni++)
    #pragma unroll
    for (int r=0;r<4;r++){
      int row = r0 + quad*4 + r, col = c0 + ni*16 + lm;
      xw[(size_t)row*NH + col] = f2bf(acc[ni][r]);
    }
}

// ---------- setup ----------

// minimal critical-path setup, branch by block range:
//   [0,1024)     : feats fp32 -> bf16 (both sides)  [needed by k_fill2 xw0]
//   [1024,1027)  : W_l transpose -> bf16            [needed by k_fill2 xw0]
//   [1027,1059)  : init ecur/cnt                    [needed by k_fill2]
__global__ __launch_bounds__(256) void k_setup(
    const float* __restrict__ fe1, const float* __restrict__ fe2,
    short* __restrict__ xf1, short* __restrict__ xf2,
    const float* __restrict__ W0, const float* __restrict__ W1, const float* __restrict__ W2,
    bf16t* __restrict__ Wt,
    int* ecur1, int* ecur2, int* cnt1, int* cnt2){
  int b = blockIdx.x, tid = threadIdx.x;
  if (b < 1024){
    int t = b*256 + tid;
    int side = t >= 131072; int i = t & 131071;
    float4 v = ((const float4*)(side? fe2:fe1))[i];
    short4 o = { (short)f2bf(v.x), (short)f2bf(v.y), (short)f2bf(v.z), (short)f2bf(v.w) };
    ((short4*)(side? xf2:xf1))[i] = o;
  } else if (b < 1027){
    int l = b - 1024;
    const float* W = (l==0)? W0 : ((l==1)? W1 : W2);
    int K = (l==0)? 64 : 128;
    bf16t* dst = Wt + ((l==0)? 0 : ((l==1)? 128*64 : 128*64+128*128));
    for (int idx = tid; idx < 128*K; idx += 256){
      int n = idx / K, k = idx - n*K;
      dst[idx] = f2bf(W[k*NH + n]);
    }
  } else {
    int t = (b-1027)*256 + tid;
    if (t < N_NODES){ ecur1[t]=0; ecur2[t]=0; }
    if (t < NB){ cnt1[t]=0; cnt2[t]=0; }
  }
}

// bucket scatter (blocks 0-1023): es=src, ec=raw ea; + batch-cnt atomics
// || layer-0 xw MFMA (blocks 1024-1535)
__global__ __launch_bounds__(256) void k_fill2(
    const int* __restrict__ ei1, const float* __restrict__ ea1,
    const int* __restrict__ ei2, const float* __restrict__ ea2,
    int* cur1, int* es1, float* ec1, int* cur2, int* es2, float* ec2,
    const int* __restrict__ b1, const int* __restrict__ b2, int* cnt1, int* cnt2,
    const bf16t* __restrict__ xf1, const bf16t* __restrict__ xf2,
    const bf16t* __restrict__ Wt, bf16t* __restrict__ xwA1, bf16t* __restrict__ xwA2){
  int blk = blockIdx.x;
  if (blk < 1024){
    int idx = blk*256 + threadIdx.x;
    int side = idx >= N_EDGES;
    int e = idx & (N_EDGES-1);
    const int* ei = side? ei2:ei1; const float* ea = side? ea2:ea1;
    int* cur = side? cur2:cur1; int* es = side? es2:es1; float* ec = side? ec2:ec1;
    int s = ei[e], d = ei[N_EDGES+e];
    int pos = atomicAdd(&cur[d], 1);
    if (pos < MAXDEG){
      es[d*MAXDEG + pos] = s;
      ec[d*MAXDEG + pos] = ea[e];
    }
    if (idx < N_NODES){ atomicAdd(&cnt1[b1[idx]],1); atomicAdd(&cnt2[b2[idx]],1); }
  } else {
    xw_body(blk-1024, threadIdx.x, xf1, xf2, 64, 64, Wt, xwA1, xwA2);
  }
}

// deg from buckets (blocks 0-63: deg[i] = 1 + sum bucket ea, no atomics)
// + batch-count scans (blocks 64,65)
__global__ __launch_bounds__(256) void k_deg2(
    const int* __restrict__ cur1, const float* __restrict__ ec1, float* deg1,
    const int* __restrict__ cur2, const float* __restrict__ ec2, float* deg2,
    const int* __restrict__ c1, const int* __restrict__ c2, int* st1, int* st2){
  __shared__ int ps[256];
  int blk = blockIdx.x, t = threadIdx.x;
  if (blk < 64){
    int idx = blk*256 + t;
    int side = idx >= N_NODES;
    int i = idx & (N_NODES-1);
    const int* cur = side? cur2:cur1;
    const float* ec = side? ec2:ec1;
    float* deg = side? deg2:deg1;
    int ce = cur[i]; if (ce > MAXDEG) ce = MAXDEG;
    float s = 1.0f;
    const float* p = ec + (size_t)i*MAXDEG;
    for (int k=0;k<ce;k++) s += p[k];
    deg[i] = s;
  } else {
    const int* c = (blk==65)? c2:c1; int* st = (blk==65)? st2:st1;
    ps[t]=c[t]; __syncthreads();
    for (int d=1; d<256; d<<=1){
      int v = (t>=d)? ps[t-d]:0;
      __syncthreads();
      ps[t]+=v;
      __syncthreads();
    }
    st[t+1]=ps[t];
    if (t==0) st[0]=0;
  }
}

// ---------- GCN ----------

// fused gather(l) + xw(l+1), one block per (side, 16-row tile); grid 1024
// coefmode=1 (layer 0): ec holds raw ea; compute coef inline and write back
__global__ __launch_bounds__(256) void k_gxw(
    const bf16t* __restrict__ xwi1, const bf16t* __restrict__ xwi2,
    const int* __restrict__ cur1, const int* __restrict__ cur2,
    const int* __restrict__ es1, const int* __restrict__ es2,
    float* __restrict__ ec1, float* __restrict__ ec2,
    const float* __restrict__ d1, const float* __restrict__ d2,
    const float* __restrict__ bias, int loff, int coefmode,
    bf16t* __restrict__ h1, bf16t* __restrict__ h2,
    const bf16t* __restrict__ Wl,
    bf16t* __restrict__ xwo1, bf16t* __restrict__ xwo2){
  int blk = blockIdx.x;
  int side = blk >> 9; int b = blk & 511;
  const ushort4* xw = (const ushort4*)(side? xwi2:xwi1);
  const int* cur = side? cur2:cur1;
  const int* es  = side? es2:es1;
  float* ec = side? ec2:ec1;
  const float* deg = side? d2:d1;
  bf16t* h = side? h2:h1;
  int t = threadIdx.x;
  int c4 = t & 31;
  float4 bv = ((const float4*)bias)[c4];
  #pragma unroll
  for (int grp=0; grp<2; grp++){
    int i = b*16 + grp*8 + (t>>5);
    float dgi = deg[i];
    float sc = 1.0f/dgi;
    float rsq_d = rsqrtf(dgi);
    ushort4 v = xw[(size_t)i*32 + c4];
    float4 acc = {b2f(v.x)*sc, b2f(v.y)*sc, b2f(v.z)*sc, b2f(v.w)*sc};
    int r = i*MAXDEG;
    int ce = cur[i]; if (ce > MAXDEG) ce = MAXDEG;
    int r1 = r + ce;
    for (; r+3<r1; r+=4){
      int s0=es[r], s1=es[r+1], s2=es[r+2], s3=es[r+3];
      float w0=ec[r], w1=ec[r+1], w2=ec[r+2], w3=ec[r+3];
      if (coefmode){
        w0 *= rsqrtf(deg[s0])*rsq_d;
        w1 *= rsqrtf(deg[s1])*rsq_d;
        w2 *= rsqrtf(deg[s2])*rsq_d;
        w3 *= rsqrtf(deg[s3])*rsq_d;
        if (c4==0){ ec[r]=w0; ec[r+1]=w1; ec[r+2]=w2; ec[r+3]=w3; }
      }
      ushort4 u0 = xw[(size_t)s0*32 + c4];
      ushort4 u1 = xw[(size_t)s1*32 + c4];
      ushort4 u2 = xw[(size_t)s2*32 + c4];
      ushort4 u3 = xw[(size_t)s3*32 + c4];
      acc.x += b2f(u0.x)*w0 + b2f(u1.x)*w1 + b2f(u2.x)*w2 + b2f(u3.x)*w3;
      acc.y += b2f(u0.y)*w0 + b2f(u1.y)*w1 + b2f(u2.y)*w2 + b2f(u3.y)*w3;
      acc.z += b2f(u0.z)*w0 + b2f(u1.z)*w1 + b2f(u2.z)*w2 + b2f(u3.z)*w3;
      acc.w += b2f(u0.w)*w0 + b2f(u1.w)*w1 + b2f(u2.w)*w2 + b2f(u3.w)*w3;
    }
    for (; r<r1; r++){
      int s0=es[r]; float w0=ec[r];
      if (coefmode){
        w0 *= rsqrtf(deg[s0])*rsq_d;
        if (c4==0) ec[r]=w0;
      }
      ushort4 u0 = xw[(size_t)s0*32 + c4];
      acc.x+=b2f(u0.x)*w0; acc.y+=b2f(u0.y)*w0; acc.z+=b2f(u0.z)*w0; acc.w+=b2f(u0.w)*w0;
    }
    acc.x+=bv.x; acc.y+=bv.y; acc.z+=bv.z; acc.w+=bv.w;
    acc.x = (acc.x>0.f)?acc.x:0.2f*acc.x;
    acc.y = (acc.y>0.f)?acc.y:0.2f*acc.y;
    acc.z = (acc.z>0.f)?acc.z:0.2f*acc.z;
    acc.w = (acc.w>0.f)?acc.w:0.2f*acc.w;
    ((ushort4*)(h + (size_t)i*D3 + loff))[c4] =
      make_ushort4(f2bf(acc.x), f2bf(acc.y), f2bf(acc.z), f2bf(acc.w));
  }
  __syncthreads();
  // xw phase: same 16 rows, K=128 from the slice just written
  int w = t>>6, lane = t&63;
  int lm = lane&15, quad = lane>>4;
  const bf16t* x = (side? h2:h1) + loff;
  int r0 = b*16;
  int c0 = w*32;
  const bf16t* a = x + (size_t)(r0+lm)*D3 + quad*8;
  bf16t* xwo = side? xwo2:xwo1;
  f32x4 acc0={0,0,0,0}, acc1={0,0,0,0};
  for (int k=0;k<128;k+=32){
    short8v af = *(const short8v*)(a + k);
    short8v b0 = *(const short8v*)(Wl + (size_t)(c0+lm)*128 + quad*8 + k);
    short8v b1 = *(const short8v*)(Wl + (size_t)(c0+16+lm)*128 + quad*8 + k);
    acc0 = __builtin_amdgcn_mfma_f32_16x16x32_bf16(af, b0, acc0, 0,0,0);
    acc1 = __builtin_amdgcn_mfma_f32_16x16x32_bf16(af, b1, acc1, 0,0,0);
  }
  #pragma unroll
  for (int r=0;r<4;r++){
    int row = r0 + quad*4 + r;
    xwo[(size_t)row*NH + c0 + lm]      = f2bf(acc0[r]);
    xwo[(size_t)row*NH + c0 + 16 + lm] = f2bf(acc1[r]);
  }
}

// fused self-loop + bucket gather + bias + leaky; layer 2 fuses l2norm -> f bf16
__global__ __launch_bounds__(256) void k_gather(const bf16t* __restrict__ xw1, const bf16t* __restrict__ xw2,
                                                const int* __restrict__ cur1, const int* __restrict__ cur2,
                                                const int* __restrict__ es1, const int* __restrict__ es2,
                                                const float* __restrict__ ec1, const float* __restrict__ ec2,
                                                const float* __restrict__ d1, const float* __restrict__ d2,
                                                const float* __restrict__ b,
                                                bf16t* __restrict__ h1, bf16t* __restrict__ h2, int loff,
                                                int l2mode, bf16t* __restrict__ f1, bf16t* __restrict__ f2){
  int blk = blockIdx.x;
  int side = blk >> 10; int bb = blk & 1023;
  const ushort4* xw = (const ushort4*)(side? xw2:xw1);
  const int* cur = side? cur2:cur1;
  const int* es  = side? es2:es1;
  const float* ec= side? ec2:ec1;
  const float* deg = side? d2:d1;
  bf16t* h = side? h2:h1;
  int t = threadIdx.x;
  int i = bb*8 + (t>>5);
  int c4 = t & 31;
  float sc = 1.0f/deg[i];
  ushort4 v = xw[(size_t)i*32 + c4];
  float4 acc = {b2f(v.x)*sc, b2f(v.y)*sc, b2f(v.z)*sc, b2f(v.w)*sc};
  int r = i*MAXDEG;
  int ce = cur[i]; if (ce > MAXDEG) ce = MAXDEG;
  int r1 = r + ce;
  for (; r+3<r1; r+=4){
    int s0=es[r], s1=es[r+1], s2=es[r+2], s3=es[r+3];
    float w0=ec[r], w1=ec[r+1], w2=ec[r+2], w3=ec[r+3];
    ushort4 u0 = xw[(size_t)s0*32 + c4];
    ushort4 u1 = xw[(size_t)s1*32 + c4];
    ushort4 u2 = xw[(size_t)s2*32 + c4];
    ushort4 u3 = xw[(size_t)s3*32 + c4];
    acc.x += b2f(u0.x)*w0 + b2f(u1.x)*w1 + b2f(u2.x)*w2 + b2f(u3.x)*w3;
    acc.y += b2f(u0.y)*w0 + b2f(u1.y)*w1 + b2f(u2.y)*w2 + b2f(u3.y)*w3;
    acc.z += b2f(u0.z)*w0 + b2f(u1.z)*w1 + b2f(u2.z)*w2 + b2f(u3.z)*w3;
    acc.w += b2f(u0.w)*w0 + b2f(u1.w)*w1 + b2f(u2.w)*w2 + b2f(u3.w)*w3;
  }
  for (; r<r1; r++){
    int s0=es[r]; float w0=ec[r];
    ushort4 u0 = xw[(size_t)s0*32 + c4];
    acc.x+=b2f(u0.x)*w0; acc.y+=b2f(u0.y)*w0; acc.z+=b2f(u0.z)*w0; acc.w+=b2f(u0.w)*w0;
  }
  float4 bv = ((const float4*)b)[c4];
  acc.x+=bv.x; acc.y+=bv.y; acc.z+=bv.z; acc.w+=bv.w;
  acc.x = (acc.x>0.f)?acc.x:0.2f*acc.x;
  acc.y = (acc.y>0.f)?acc.y:0.2f*acc.y;
  acc.z = (acc.z>0.f)?acc.z:0.2f*acc.z;
  acc.w = (acc.w>0.f)?acc.w:0.2f*acc.w;
  if (!l2mode){
    ((ushort4*)(h + (size_t)i*D3 + loff))[c4] =
      make_ushort4(f2bf(acc.x), f2bf(acc.y), f2bf(acc.z), f2bf(acc.w));
  } else {
    ushort4 u0 = ((const ushort4*)(h + (size_t)i*D3))[c4];
    ushort4 u1 = ((const ushort4*)(h + (size_t)i*D3 + 128))[c4];
    float4 v0 = {b2f(u0.x), b2f(u0.y), b2f(u0.z), b2f(u0.w)};
    float4 v1 = {b2f(u1.x), b2f(u1.y), b2f(u1.z), b2f(u1.w)};
    float ss = v0.x*v0.x+v0.y*v0.y+v0.z*v0.z+v0.w*v0.w
             + v1.x*v1.x+v1.y*v1.y+v1.z*v1.z+v1.w*v1.w
             + acc.x*acc.x+acc.y*acc.y+acc.z*acc.z+acc.w*acc.w;
    #pragma unroll
    for (int m=1;m<32;m<<=1) ss += __shfl_xor(ss, m, 64);   // 32-lane node group
    float scale = 1.0f/fmaxf(sqrtf(ss), 1e-12f);
    bf16t* f = side? f2:f1;
    ((ushort4*)(f + (size_t)i*D6))[c4]       = make_ushort4(f2bf(v0.x*scale),f2bf(v0.y*scale),f2bf(v0.z*scale),f2bf(v0.w*scale));
    ((ushort4*)(f + (size_t)i*D6 + 128))[c4] = make_ushort4(f2bf(v1.x*scale),f2bf(v1.y*scale),f2bf(v1.z*scale),f2bf(v1.w*scale));
    ((ushort4*)(f + (size_t)i*D6 + 256))[c4] = make_ushort4(f2bf(acc.x*scale),f2bf(acc.y*scale),f2bf(acc.z*scale),f2bf(acc.w*scale));
  }
}

// ---------- interaction fused + step-1 attention tail + co-dispatched late-setup ----------
// 512 threads (8 waves); blocks:
//   [0,512)      : per-(graph,side): phase A S via MFMA into LDS; phase B weighted
//                  row-gather (dst[:,384:768] = S.src[:,0:384]); step-1 att tail
//   [512,1664)   : Wih right half -> bf16 (1152 blocks x 512t)
//   [1664,2048)  : Wp1 fp32 -> bf16 (384 blocks)
//   [2048,2432)  : cvec, 8 j/block (384 blocks)
__global__ __launch_bounds__(512) void k_inter(bf16t* __restrict__ f1, bf16t* __restrict__ f2,
                                               const int* __restrict__ st1, const int* __restrict__ st2,
                                               const float* __restrict__ bih, const float* __restrict__ bhh,
                                               bf16t* __restrict__ Ab,
                                               const float* __restrict__ Wih, short* __restrict__ Wih16,
                                               const float* __restrict__ Wp1, short* __restrict__ Wp116,
                                               const float* __restrict__ Whh, float* __restrict__ cvec){
  __shared__ __align__(16) float smem[7008];   // 28032 B; Sld / att-tail / cvec-h0 alias
  bf16t* Sld = (bf16t*)smem;
  int bx = blockIdx.x;
  int t = threadIdx.x;
  int w = t>>6, lane = t&63;
  if (bx >= 512){
    if (bx < 1664){
      int tt = (bx-512)*512 + t;
      int n = tt/192, q = tt - n*192;
      float4 v = ((const float4*)(Wih + (size_t)n*1536 + 768))[q];
      short4 o = { (short)f2bf(v.x), (short)f2bf(v.y), (short)f2bf(v.z), (short)f2bf(v.w) };
      ((short4*)Wih16)[tt] = o;
    } else if (bx < 2048){
      int tt = (bx-1664)*512 + t;
      float4 v = ((const float4*)Wp1)[tt];
      short4 o = { (short)f2bf(v.x), (short)f2bf(v.y), (short)f2bf(v.z), (short)f2bf(v.w) };
      ((short4*)Wp116)[tt] = o;
    } else {
      int j0 = (bx - 2048)*8;
      for (int k=t; k<D6; k+=512) smem[k] = h0val(bih,bhh,k);
      __syncthreads();
      int j = j0 + w;
      const float4* wi = (const float4*)(Wih + (size_t)j*(2*D6));
      const float4* wh = (const float4*)(Whh + (size_t)j*D6);
      const float4* h4 = (const float4*)smem;
      float acc=0;
      #pragma unroll
      for (int m=0;m<3;m++){
        float4 hv = h4[m*64+lane];
        float4 a = wi[m*64+lane];
        float4 bb = wh[m*64+lane];
        acc += hv.x*(a.x+bb.x) + hv.y*(a.y+bb.y) + hv.z*(a.z+bb.z) + hv.w*(a.w+bb.w);
      }
      #pragma unroll
      for (int m=1;m<64;m<<=1) acc += __shfl_xor(acc,m,64);
      if (lane==0) cvec[j]=acc+bih[j]+bhh[j];
    }
    return;
  }
  int side = bx >> 8, g = bx & (NB-1);
  int i0 = st1[g]; int n1 = st1[g+1]-i0; if (n1>SMM) n1=SMM;
  int j0 = st2[g]; int n2 = st2[g+1]-j0; if (n2>SMM) n2=SMM;
  int cnt = side? n2 : n1;
  int J   = side? n1 : n2;
  int r0base = side? j0 : i0;
  int c0base = side? i0 : j0;
  const bf16t* rowp = (side? f2 : f1);
  const bf16t* colp = (side? f1 : f2);
  const bf16t* src = colp + (size_t)c0base*D6;
  bf16t* dst = (side? f2 : f1) + (size_t)r0base*D6 + D3;
  int lm = lane & 15, quad = lane >> 4;
  // phase A: S tiles via MFMA into LDS (write-mask covers all phase-B reads)
  int nti = (cnt+15)>>4, ntj = (J+15)>>4;
  for (int tile = w; tile < nti*ntj; tile += 8){
    int ti = tile/ntj, tj = tile - ti*ntj;
    int ar = r0base + ti*16 + lm; if (ar > N_NODES-1) ar = N_NODES-1;
    int br = c0base + tj*16 + lm; if (br > N_NODES-1) br = N_NODES-1;
    const bf16t* a = rowp + (size_t)ar*D6 + quad*8;
    const bf16t* b = colp + (size_t)br*D6 + quad*8;
    f32x4 acc = {0,0,0,0};
    #pragma unroll
    for (int k=0; k<384; k+=32){
      short8v af = *(const short8v*)(a + k);
      short8v bf = *(const short8v*)(b + k);
      acc = __builtin_amdgcn_mfma_f32_16x16x32_bf16(af, bf, acc, 0, 0, 0);
    }
    int col = tj*16 + lm;
    #pragma unroll
    for (int r=0;r<4;r++){
      int row = ti*16 + quad*4 + r;
      if (row < cnt && col < J)
        Sld[row*SLD + col] = f2bf(acc[r]);
    }
  }
  __syncthreads();
  // phase B: weighted row-gather over first 384 channels of src, one row per wave
  for (int row = w; row < cnt; row += 8){
    float acc[6] = {};
    const bf16t* sr = Sld + row*SLD;
    for (int j = 0; j < J; j++){
      float s = b2f(sr[j]);
      const uint* xr = (const uint*)(src + (size_t)j*D6);
      #pragma unroll
      for (int m=0;m<3;m++){
        uint rv = xr[m*64+lane];
        acc[m*2+0] += s*bfl(rv);
        acc[m*2+1] += s*bfh(rv);
      }
    }
    #pragma unroll
    for (int m=0;m<3;m++)
      ((ushort2*)(dst + (size_t)row*D6 + m*128))[lane] =
        make_ushort2(f2bf(acc[m*2]), f2bf(acc[m*2+1]));
  }
  // ---- step-1 attention tail; smem re-aliased as hs/e_s/part[8] ----
  __syncthreads();
  {
    float4* hs = (float4*)smem;                // 192 float4 = 3072 B
    float* e_s = smem + 768;                   // 96 floats
    float* part = smem + 864;                  // 8*768 floats -> ends at 28032 B
    const bf16t* x = rowp + (size_t)r0base*D6;
    if (t<192){
      int j = t*4;
      hs[t] = make_float4(h0val(bih,bhh,j), h0val(bih,bhh,j+1), h0val(bih,bhh,j+2), h0val(bih,bhh,j+3));
    }
    __syncthreads();
    for (int n=w; n<cnt; n+=8){
      const uint2* xr = (const uint2*)(x + (size_t)n*D6);
      float p = 0;
      #pragma unroll
      for (int m=0;m<3;m++){
        uint2 rv = xr[m*64+lane];
        float4 hvv = hs[m*64+lane];
        p += bfl(rv.x)*hvv.x + bfh(rv.x)*hvv.y + bfl(rv.y)*hvv.z + bfh(rv.y)*hvv.w;
      }
      #pragma unroll
      for (int m=1;m<64;m<<=1) p += __shfl_xor(p,m,64);
      if (lane==0) e_s[n]=p;
    }
    __syncthreads();
    if (w==0){
      float mx=-INFINITY;
      for (int n=lane;n<cnt;n+=64) mx=fmaxf(mx,e_s[n]);
      #pragma unroll
      for (int m=1;m<64;m<<=1) mx=fmaxf(mx,__shfl_xor(mx,m,64));
      float s=0;
      for (int n=lane;n<cnt;n+=64) s+=__expf(e_s[n]-mx);
      #pragma unroll
      for (int m=1;m<64;m<<=1) s+=__shfl_xor(s,m,64);
      float inv=1.0f/s;
      for (int n=lane;n<cnt;n+=64) e_s[n]=__expf(e_s[n]-mx)*inv;
    }
    __syncthreads();
    float av[3][4] = {};
    for (int n=w; n<cnt; n+=8){
      float a = e_s[n];
      const uint2* xr = (const uint2*)(x + (size_t)n*D6);
      #pragma unroll
      for (int m=0;m<3;m++){
        uint2 rv = xr[m*64+lane];
        av[m][0]+=a*bfl(rv.x); av[m][1]+=a*bfh(rv.x); av[m][2]+=a*bfl(rv.y); av[m][3]+=a*bfh(rv.y);
      }
    }
    #pragma unroll
    for (int m=0;m<3;m++)
      *(float4*)&part[w*D6 + (m*64+lane)*4] = make_float4(av[m][0],av[m][1],av[m][2],av[m][3]);
    __syncthreads();
    if (t<192){
      float4 s = make_float4(0.f,0.f,0.f,0.f);
      #pragma unroll
      for (int p8=0;p8<8;p8++){
        float4 pv = *(const float4*)&part[p8*D6 + t*4];
        s.x+=pv.x; s.y+=pv.y; s.z+=pv.z; s.w+=pv.w;
      }
      ushort4 o = make_ushort4(f2bf(s.x), f2bf(s.y), f2bf(s.z), f2bf(s.w));
      ((ushort4*)(Ab + (size_t)(side*NB+g)*D6))[t]=o;
    }
  }
}

// ---------- set2set ----------

// fused attention: e=x.hv, segment softmax, r=sum a*x (wave-parallel); x bf16; r bf16
__global__ __launch_bounds__(256) void k_att(const bf16t* __restrict__ f1, const bf16t* __restrict__ f2,
                                             const float* __restrict__ hbase, int perseg,
                                             const float* __restrict__ bih, const float* __restrict__ bhh,
                                             const int* __restrict__ st1, const int* __restrict__ st2,
                                             bf16t* __restrict__ dst16, long sidestep, long dstride){
  __shared__ float4 hs[192];
  __shared__ float e_s[SMM];
  __shared__ float part[4][D6];
  int side = blockIdx.x >> 8, g = blockIdx.x & (NB-1);
  const int* st = side? st2:st1;
  int n0 = st[g]; int cnt = st[g+1]-n0; if (cnt>SMM) cnt=SMM;
  const bf16t* x = (side? f2:f1) + (size_t)n0*D6;
  int t = threadIdx.x, w = t>>6, lane = t&63;
  if (t<192){
    if (perseg){
      hs[t] = ((const float4*)(hbase + (size_t)(side*NB+g)*D6))[t];
    } else {
      int j = t*4;
      hs[t] = make_float4(h0val(bih,bhh,j), h0val(bih,bhh,j+1), h0val(bih,bhh,j+2), h0val(bih,bhh,j+3));
    }
  }
  __syncthreads();
  for (int n=w; n<cnt; n+=4){
    const uint2* xr = (const uint2*)(x + (size_t)n*D6);
    float p = 0;
    #pragma unroll
    for (int m=0;m<3;m++){
      uint2 rv = xr[m*64+lane];
      float4 hvv = hs[m*64+lane];
      p += bfl(rv.x)*hvv.x + bfh(rv.x)*hvv.y + bfl(rv.y)*hvv.z + bfh(rv.y)*hvv.w;
    }
    #pragma unroll
    for (int m=1;m<64;m<<=1) p += __shfl_xor(p,m,64);
    if (lane==0) e_s[n]=p;
  }
  __syncthreads();
  if (w==0){
    float mx=-INFINITY;
    for (int n=lane;n<cnt;n+=64) mx=fmaxf(mx,e_s[n]);
    #pragma unroll
    for (int m=1;m<64;m<<=1) mx=fmaxf(mx,__shfl_xor(mx,m,64));
    float s=0;
    for (int n=lane;n<cnt;n+=64) s+=__expf(e_s[n]-mx);
    #pragma unroll
    for (int m=1;m<64;m<<=1) s+=__shfl_xor(s,m,64);
    float inv=1.0f/s;
    for (int n=lane;n<cnt;n+=64) e_s[n]=__expf(e_s[n]-mx)*inv;
  }
  __syncthreads();
  float av[3][4] = {};
  for (int n=w; n<cnt; n+=4){
    float a = e_s[n];
    const uint2* xr = (const uint2*)(x + (size_t)n*D6);
    #pragma unroll
    for (int m=0;m<3;m++){
      uint2 rv = xr[m*64+lane];
      av[m][0]+=a*bfl(rv.x); av[m][1]+=a*bfh(rv.x); av[m][2]+=a*bfl(rv.y); av[m][3]+=a*bfh(rv.y);
    }
  }
  #pragma unroll
  for (int m=0;m<3;m++)
    *(float4*)&part[w][(m*64+lane)*4] = make_float4(av[m][0],av[m][1],av[m][2],av[m][3]);
  __syncthreads();
  if (t<192){
    float4 p0 = *(const float4*)&part[0][t*4];
    float4 p1 = *(const float4*)&part[1][t*4];
    float4 p2 = *(const float4*)&part[2][t*4];
    float4 p3 = *(const float4*)&part[3][t*4];
    float4 s = make_float4(p0.x+p1.x+p2.x+p3.x, p0.y+p1.y+p2.y+p3.y,
                           p0.z+p1.z+p2.z+p3.z, p0.w+p1.w+p2.w+p3.w);
    ushort4 o = make_ushort4(f2bf(s.x), f2bf(s.y), f2bf(s.z), f2bf(s.w));
    ushort4* dp = (ushort4*)(dst16 + side*sidestep + (size_t)g*dstride);
    dp[t]=o;
  }
}

// fused gates GEMM + LSTM step-1 pointwise: wave w computes gate w for (16m x 64j) tile
__global__ __launch_bounds__(256) void k_gates(const short* __restrict__ A16,
                                               const short* __restrict__ B16,
                                               const float* __restrict__ cvec,
                                               const float* __restrict__ bih, const float* __restrict__ bhh,
                                               float* __restrict__ h1s, bf16t* __restrict__ z16){
  __shared__ float gbuf[4][16][66];
  int w = threadIdx.x >> 6, lane = threadIdx.x & 63;
  int lm = lane & 15, quad = lane >> 4;
  int bm = blockIdx.x * 16;
  int jb = blockIdx.y * 64;
  const short* a = A16 + (size_t)(bm + lm)*768 + quad*8;
  const short* b = B16 + (size_t)(w*768 + jb + lm)*768 + quad*8;
  f32x4 acc0={0,0,0,0}, acc1={0,0,0,0}, acc2={0,0,0,0}, acc3={0,0,0,0};
  for (int k=0; k<768; k+=32){
    short8v af = *(const short8v*)(a + k);
    short8v b0 = *(const short8v*)(b + k);
    short8v b1 = *(const short8v*)(b + 16*768 + k);
    short8v b2 = *(const short8v*)(b + 32*768 + k);
    short8v b3 = *(const short8v*)(b + 48*768 + k);
    acc0 = __builtin_amdgcn_mfma_f32_16x16x32_bf16(af, b0, acc0, 0, 0, 0);
    acc1 = __builtin_amdgcn_mfma_f32_16x16x32_bf16(af, b1, acc1, 0, 0, 0);
    acc2 = __builtin_amdgcn_mfma_f32_16x16x32_bf16(af, b2, acc2, 0, 0, 0);
    acc3 = __builtin_amdgcn_mfma_f32_16x16x32_bf16(af, b3, acc3, 0, 0, 0);
  }
  #pragma unroll
  for (int r=0;r<4;r++){
    gbuf[w][quad*4+r][lm]      = acc0[r];
    gbuf[w][quad*4+r][16+lm]   = acc1[r];
    gbuf[w][quad*4+r][32+lm]   = acc2[r];
    gbuf[w][quad*4+r][48+lm]   = acc3[r];
  }
  __syncthreads();
  int t = threadIdx.x;
  #pragma unroll
  for (int u=0; u<4; u++){
    int p = t + u*256;
    int mm = p>>6, jj = p&63;
    int j = jb + jj, m = bm + mm;
    float g4[4];
    #pragma unroll
    for (int q=0;q<4;q++) g4[q] = gbuf[q][mm][jj] + cvec[q*D6 + j];
    float c0j = sigf(bih[j]+bhh[j]) * tanhf(bih[2*D6+j]+bhh[2*D6+j]);
    float c = sigf(g4[1])*c0j + sigf(g4[0])*tanhf(g4[2]);
    float h = sigf(g4[3])*tanhf(c);
    h1s[(size_t)m*D6 + j] = h;
    int side = m>>8, g = m&255;
    z16[(size_t)g*3072 + side*1536 + j] = f2bf(h);
  }
}

// p1 GEMM via MFMA, split-K=16: pout[z][256x256]
__global__ __launch_bounds__(256) void k_gemm_mfma_p1(const short* __restrict__ A16,
                                                      const short* __restrict__ B16,
                                                      float* __restrict__ pout){
  int w = threadIdx.x >> 6, lane = threadIdx.x & 63;
  int lm = lane & 15, quad = lane >> 4;
  int bm = blockIdx.x * 16;
  int bn = w * 64;
  int kbase = blockIdx.y * 192;
  const short* a = A16 + (size_t)(bm + lm)*3072 + quad*8 + kbase;
  const short* b = B16 + (size_t)(bn + lm)*3072 + quad*8 + kbase;
  f32x4 acc0={0,0,0,0}, acc1={0,0,0,0}, acc2={0,0,0,0}, acc3={0,0,0,0};
  for (int k=0; k<192; k+=32){
    short8v af = *(const short8v*)(a + k);
    short8v b0 = *(const short8v*)(b + k);
    short8v b1 = *(const short8v*)(b + 16*3072 + k);
    short8v b2 = *(const short8v*)(b + 32*3072 + k);
    short8v b3 = *(const short8v*)(b + 48*3072 + k);
    acc0 = __builtin_amdgcn_mfma_f32_16x16x32_bf16(af, b0, acc0, 0, 0, 0);
    acc1 = __builtin_amdgcn_mfma_f32_16x16x32_bf16(af, b1, acc1, 0, 0, 0);
    acc2 = __builtin_amdgcn_mfma_f32_16x16x32_bf16(af, b2, acc2, 0, 0, 0);
    acc3 = __builtin_amdgcn_mfma_f32_16x16x32_bf16(af, b3, acc3, 0, 0, 0);
  }
  float* po = pout + (size_t)blockIdx.y*256*256;
  #pragma unroll
  for (int r=0;r<4;r++){
    size_t base = (size_t)(bm + quad*4 + r)*256 + bn + lm;
    po[base]      = acc0[r];
    po[base + 16] = acc1[r];
    po[base + 32] = acc2[r];
    po[base + 48] = acc3[r];
  }
}

// fused p1-reduce + p2 + p3: block per batch row
__global__ __launch_bounds__(128) void k_p23(const float* __restrict__ pbuf, const float* __restrict__ bp1,
                                             const float* __restrict__ Wp2, const float* __restrict__ bp2,
                                             const float* __restrict__ Wp3, const float* __restrict__ bp3,
                                             float* __restrict__ out){
  __shared__ float zr[256];
  __shared__ float ws[2];
  int m = blockIdx.x, t = threadIdx.x;
  float2 zacc = ((const float2*)(bp1))[t];
  #pragma unroll
  for (int p=0;p<16;p++){
    float2 v = ((const float2*)(pbuf + (size_t)p*256*256 + (size_t)m*256))[t];
    zacc.x += v.x; zacc.y += v.y;
  }
  zr[2*t]   = fmaxf(zacc.x, 0.f);
  zr[2*t+1] = fmaxf(zacc.y, 0.f);
  __syncthreads();
  const float4* wrow = (const float4*)(Wp2 + (size_t)t*256);
  const float4* z4 = (const float4*)zr;
  float acc = bp2[t];
  #pragma unroll 8
  for (int k=0;k<64;k++){
    float4 wv = wrow[k], zv = z4[k];
    acc += wv.x*zv.x + wv.y*zv.y + wv.z*zv.z + wv.w*zv.w;
  }
  float p = fmaxf(acc,0.f)*Wp3[t];
  #pragma unroll
  for (int o=32;o;o>>=1) p += __shfl_down(p,o,64);
  if ((t&63)==0) ws[t>>6]=p;
  __syncthreads();
  if (t==0){ float v=ws[0]+ws[1]+bp3[0]; out[m]=1.0f/(1.0f+__expf(-v)); }
}

// ---------- launch ----------

extern "C" void kernel_launch(void* const* d_in, const int* in_sizes, int n_in,
                              void* d_out, int out_size, void* d_ws, size_t ws_size,
                              hipStream_t stream){
  const float* feat1=(const float*)d_in[0];
  const float* feat2=(const float*)d_in[1];
  const float* ea1  =(const float*)d_in[2];
  const float* ea2  =(const float*)d_in[3];
  const float* W0=(const float*)d_in[4];  const float* b0=(const float*)d_in[5];
  const float* W1=(const float*)d_in[6];  const float* b1=(const float*)d_in[7];
  const float* W2=(const float*)d_in[8];  const float* b2=(const float*)d_in[9];
  const float* Wih=(const float*)d_in[10]; const float* bih=(const float*)d_in[11];
  const float* Whh=(const float*)d_in[12]; const float* bhh=(const float*)d_in[13];
  const float* Wp1=(const float*)d_in[14]; const float* bp1=(const float*)d_in[15];
  const float* Wp2=(const float*)d_in[16]; const float* bp2=(const float*)d_in[17];
  const float* Wp3=(const float*)d_in[18]; const float* bp3=(const float*)d_in[19];
  const int* ei1=(const int*)d_in[20]; const int* ei2=(const int*)d_in[21];
  const int* batch1=(const int*)d_in[22]; const int* batch2=(const int*)d_in[23];
  float* out = (float*)d_out;

  float* base = (float*)d_ws;
  size_t off = 0;
  auto alloc = [&](size_t n)->float* { float* r = base + off; off += (n + 255) & ~(size_t)255; return r; };
  float* deg1 = alloc(N_NODES);          float* deg2 = alloc(N_NODES);
  bf16t* xwA1 = (bf16t*)alloc((size_t)N_NODES*NH/2);
  bf16t* xwA2 = (bf16t*)alloc((size_t)N_NODES*NH/2);
  bf16t* xwB1 = (bf16t*)alloc((size_t)N_NODES*NH/2);
  bf16t* xwB2 = (bf16t*)alloc((size_t)N_NODES*NH/2);
  bf16t* hb1  = (bf16t*)alloc((size_t)N_NODES*D3/2);
  bf16t* hb2  = (bf16t*)alloc((size_t)N_NODES*D3/2);
  bf16t* xf1  = (bf16t*)alloc((size_t)N_NODES*64/2);
  bf16t* xf2  = (bf16t*)alloc((size_t)N_NODES*64/2);
  bf16t* Wtb  = (bf16t*)alloc((size_t)(128*64 + 2*128*128)/2);
  bf16t* f1   = (bf16t*)alloc((size_t)N_NODES*D6/2);
  bf16t* f2   = (bf16t*)alloc((size_t)N_NODES*D6/2);
  float* ecoef1 = alloc((size_t)N_NODES*MAXDEG);  float* ecoef2 = alloc((size_t)N_NODES*MAXDEG);
  float* cvec = alloc(4*D6);
  float* h1s  = alloc((size_t)512*D6);
  bf16t* zbuf16 = (bf16t*)alloc((size_t)256*3072/2);
  float* pbuf = alloc((size_t)16*256*256);
  short* Abuf16 = (short*)alloc((size_t)512*D6/2);
  short* Wih16  = (short*)alloc((size_t)3072*D6/2);
  short* Wp116  = (short*)alloc((size_t)256*3072/2);
  int* cnt1 = (int*)alloc(NB);   int* cnt2 = (int*)alloc(NB);
  int* st1  = (int*)alloc(NB+1); int* st2  = (int*)alloc(NB+1);
  int* ecur1= (int*)alloc(N_NODES); int* ecur2 = (int*)alloc(N_NODES);
  int* esrc1= (int*)alloc((size_t)N_NODES*MAXDEG); int* esrc2 = (int*)alloc((size_t)N_NODES*MAXDEG);
  (void)ws_size; (void)in_sizes; (void)n_in; (void)out_size;

  // minimal setup; bucket scatter||xw0; deg-from-buckets + scans
  k_setup  <<<1059,256,0,stream>>>(feat1,feat2,(short*)xf1,(short*)xf2,
                                   W0,W1,W2,Wtb, ecur1,ecur2,cnt1,cnt2);
  k_fill2  <<<1536,256,0,stream>>>(ei1,ea1, ei2,ea2,
                                   ecur1,esrc1,ecoef1, ecur2,esrc2,ecoef2,
                                   batch1,batch2,cnt1,cnt2,
                                   xf1,xf2,Wtb,xwA1,xwA2);
  k_deg2   <<<66,256,0,stream>>>(ecur1,ecoef1,deg1, ecur2,ecoef2,deg2,
                                 cnt1,cnt2,st1,st2);

  const bf16t* Wt1 = Wtb + 128*64;
  const bf16t* Wt2 = Wtb + 128*64 + 128*128;
  // gather0 (coef inline + write-back) + xw1
  k_gxw<<<1024,256,0,stream>>>(xwA1,xwA2, ecur1,ecur2, esrc1,esrc2, ecoef1,ecoef2,
                               deg1,deg2, b0, 0, 1, hb1,hb2, Wt1, xwB1,xwB2);
  // gather1 + xw2
  k_gxw<<<1024,256,0,stream>>>(xwB1,xwB2, ecur1,ecur2, esrc1,esrc2, ecoef1,ecoef2,
                               deg1,deg2, b1, NH, 0, hb1,hb2, Wt2, xwA1,xwA2);
  // gather2 (l2norm -> f)
  k_gather <<<2048,256,0,stream>>>(xwA1,xwA2,ecur1,ecur2,esrc1,esrc2,ecoef1,ecoef2,
                                   deg1,deg2,b2,hb1,hb2,2*NH,1,f1,f2);

  // fused interaction (512t, 8 waves) || Wih16/Wp116 converts || cvec
  k_inter <<<2432,512,0,stream>>>(f1,f2,st1,st2,bih,bhh,(bf16t*)Abuf16,
                                  Wih,(short*)Wih16, Wp1,(short*)Wp116, Whh,cvec);

  // fused gates GEMM + LSTM step-1 pointwise
  k_gates<<<dim3(32,12),256,0,stream>>>(Abuf16, Wih16, cvec, bih, bhh, h1s, zbuf16);

  // step-2 attention (per-segment h) -> zbuf16 r-slots
  k_att<<<512,256,0,stream>>>(f1,f2,h1s,1,bih,bhh,st1,st2,
                              zbuf16+768,(long)1536,(long)3072);

  // MLP: p1 via MFMA (split-K=16); fused reduce+p2+p3
  k_gemm_mfma_p1<<<dim3(16,16),256,0,stream>>>((const short*)zbuf16, Wp116, pbuf);
  k_p23 <<<256,128,0,stream>>>(pbuf, bp1, Wp2, bp2, Wp3, bp3, out);
}

// Round 18
// 318.929 us; speedup vs baseline: 1.0797x; 1.0302x over previous
//
#include <hip/hip_runtime.h>
#include <cmath>

#define N_NODES 8192
#define N_EDGES 131072
#define NB      256
#define NH      128
#define D3      384
#define D6      768
#define SMM     96   // max nodes per (graph,side)
#define SLD     104  // LDS stride for S (96 + 8 pad)
#define MAXDEG  64   // bucket capacity per dst node; Binomial mean 16, 64 = +12 sigma

typedef __attribute__((ext_vector_type(8))) short short8v;
typedef __attribute__((ext_vector_type(4))) float f32x4;
typedef unsigned short bf16t;

__device__ __forceinline__ float sigf(float x){ return 1.0f/(1.0f+__expf(-x)); }
__device__ __forceinline__ unsigned short f2bf(float x){
  unsigned u = __float_as_uint(x);
  unsigned r = u + 0x7FFF + ((u>>16)&1);   // round-to-nearest-even
  return (unsigned short)(r>>16);
}
__device__ __forceinline__ float bfl(unsigned u){ return __uint_as_float(u<<16); }
__device__ __forceinline__ float bfh(unsigned u){ return __uint_as_float(u & 0xFFFF0000u); }
__device__ __forceinline__ float b2f(bf16t u){ return __uint_as_float(((unsigned)u)<<16); }
// h0[j] from LSTM step-0 collapse (q_star=h=c=0)
__device__ __forceinline__ float h0val(const float* bih, const float* bhh, int j){
  float c = sigf(bih[j]+bhh[j]) * tanhf(bih[2*D6+j]+bhh[2*D6+j]);
  return sigf(bih[3*D6+j]+bhh[3*D6+j]) * tanhf(c);
}

// xw = x @ W via MFMA (device body); x bf16 row stride xs, Wt bf16 [128][K]
// vb in [0,512): side*256+b; 4 waves = 32 rows x 128 cols
__device__ __forceinline__ void xw_body(int vb, int t,
    const bf16t* __restrict__ x1, const bf16t* __restrict__ x2, int xs, int K,
    const bf16t* __restrict__ Wt, bf16t* __restrict__ xw1, bf16t* __restrict__ xw2){
  int side = vb >> 8; int b = vb & 255;
  const bf16t* x = side? x2:x1;
  bf16t* xw = side? xw2:xw1;
  int w = t>>6, lane = t&63;
  int lm = lane&15, quad = lane>>4;
  int r0 = b*32 + (w>>1)*16;
  int c0 = (w&1)*64;
  const bf16t* a = x + (size_t)(r0+lm)*xs + quad*8;
  f32x4 acc[4] = {};
  for (int k=0;k<K;k+=32){
    short8v af = *(const short8v*)(a + k);
    #pragma unroll
    for (int ni=0;ni<4;ni++){
      short8v bf = *(const short8v*)(Wt + (size_t)(c0+ni*16+lm)*K + quad*8 + k);
      acc[ni] = __builtin_amdgcn_mfma_f32_16x16x32_bf16(af, bf, acc[ni], 0,0,0);
    }
  }
  #pragma unroll
  for (int ni=0;ni<4;ni++)
    #pragma unroll
    for (int r=0;r<4;r++){
      int row = r0 + quad*4 + r, col = c0 + ni*16 + lm;
      xw[(size_t)row*NH + col] = f2bf(acc[ni][r]);
    }
}

// ---------- setup ----------

// minimal critical-path setup, branch by block range:
//   [0,1024)     : feats fp32 -> bf16 (both sides)  [needed by k_fill2 xw0]
//   [1024,1027)  : W_l transpose -> bf16            [needed by k_fill2 xw0]
//   [1027,1059)  : init ecur/cnt                    [needed by k_fill2]
__global__ __launch_bounds__(256) void k_setup(
    const float* __restrict__ fe1, const float* __restrict__ fe2,
    short* __restrict__ xf1, short* __restrict__ xf2,
    const float* __restrict__ W0, const float* __restrict__ W1, const float* __restrict__ W2,
    bf16t* __restrict__ Wt,
    int* ecur1, int* ecur2, int* cnt1, int* cnt2){
  int b = blockIdx.x, tid = threadIdx.x;
  if (b < 1024){
    int t = b*256 + tid;
    int side = t >= 131072; int i = t & 131071;
    float4 v = ((const float4*)(side? fe2:fe1))[i];
    short4 o = { (short)f2bf(v.x), (short)f2bf(v.y), (short)f2bf(v.z), (short)f2bf(v.w) };
    ((short4*)(side? xf2:xf1))[i] = o;
  } else if (b < 1027){
    int l = b - 1024;
    const float* W = (l==0)? W0 : ((l==1)? W1 : W2);
    int K = (l==0)? 64 : 128;
    bf16t* dst = Wt + ((l==0)? 0 : ((l==1)? 128*64 : 128*64+128*128));
    for (int idx = tid; idx < 128*K; idx += 256){
      int n = idx / K, k = idx - n*K;
      dst[idx] = f2bf(W[k*NH + n]);
    }
  } else {
    int t = (b-1027)*256 + tid;
    if (t < N_NODES){ ecur1[t]=0; ecur2[t]=0; }
    if (t < NB){ cnt1[t]=0; cnt2[t]=0; }
  }
}

// bucket scatter (blocks 0-1023): es=src, ec=raw ea; + batch-cnt atomics
// || layer-0 xw MFMA (blocks 1024-1535)
__global__ __launch_bounds__(256) void k_fill2(
    const int* __restrict__ ei1, const float* __restrict__ ea1,
    const int* __restrict__ ei2, const float* __restrict__ ea2,
    int* cur1, int* es1, float* ec1, int* cur2, int* es2, float* ec2,
    const int* __restrict__ b1, const int* __restrict__ b2, int* cnt1, int* cnt2,
    const bf16t* __restrict__ xf1, const bf16t* __restrict__ xf2,
    const bf16t* __restrict__ Wt, bf16t* __restrict__ xwA1, bf16t* __restrict__ xwA2){
  int blk = blockIdx.x;
  if (blk < 1024){
    int idx = blk*256 + threadIdx.x;
    int side = idx >= N_EDGES;
    int e = idx & (N_EDGES-1);
    const int* ei = side? ei2:ei1; const float* ea = side? ea2:ea1;
    int* cur = side? cur2:cur1; int* es = side? es2:es1; float* ec = side? ec2:ec1;
    int s = ei[e], d = ei[N_EDGES+e];
    int pos = atomicAdd(&cur[d], 1);
    if (pos < MAXDEG){
      es[d*MAXDEG + pos] = s;
      ec[d*MAXDEG + pos] = ea[e];
    }
    if (idx < N_NODES){ atomicAdd(&cnt1[b1[idx]],1); atomicAdd(&cnt2[b2[idx]],1); }
  } else {
    xw_body(blk-1024, threadIdx.x, xf1, xf2, 64, 64, Wt, xwA1, xwA2);
  }
}

// deg from buckets (blocks 0-63: deg[i] = 1 + sum bucket ea, no atomics)
// + batch-count scans (blocks 64,65)
__global__ __launch_bounds__(256) void k_deg2(
    const int* __restrict__ cur1, const float* __restrict__ ec1, float* deg1,
    const int* __restrict__ cur2, const float* __restrict__ ec2, float* deg2,
    const int* __restrict__ c1, const int* __restrict__ c2, int* st1, int* st2){
  __shared__ int ps[256];
  int blk = blockIdx.x, t = threadIdx.x;
  if (blk < 64){
    int idx = blk*256 + t;
    int side = idx >= N_NODES;
    int i = idx & (N_NODES-1);
    const int* cur = side? cur2:cur1;
    const float* ec = side? ec2:ec1;
    float* deg = side? deg2:deg1;
    int ce = cur[i]; if (ce > MAXDEG) ce = MAXDEG;
    float s = 1.0f;
    const float* p = ec + (size_t)i*MAXDEG;
    for (int k=0;k<ce;k++) s += p[k];
    deg[i] = s;
  } else {
    const int* c = (blk==65)? c2:c1; int* st = (blk==65)? st2:st1;
    ps[t]=c[t]; __syncthreads();
    for (int d=1; d<256; d<<=1){
      int v = (t>=d)? ps[t-d]:0;
      __syncthreads();
      ps[t]+=v;
      __syncthreads();
    }
    st[t+1]=ps[t];
    if (t==0) st[0]=0;
  }
}

// ---------- GCN ----------

// fused gather(l) + xw(l+1), one block per (side, 16-row tile); grid 1024
// coefmode=1 (layer 0): ec holds raw ea; compute coef inline and write back
__global__ __launch_bounds__(256) void k_gxw(
    const bf16t* __restrict__ xwi1, const bf16t* __restrict__ xwi2,
    const int* __restrict__ cur1, const int* __restrict__ cur2,
    const int* __restrict__ es1, const int* __restrict__ es2,
    float* __restrict__ ec1, float* __restrict__ ec2,
    const float* __restrict__ d1, const float* __restrict__ d2,
    const float* __restrict__ bias, int loff, int coefmode,
    bf16t* __restrict__ h1, bf16t* __restrict__ h2,
    const bf16t* __restrict__ Wl,
    bf16t* __restrict__ xwo1, bf16t* __restrict__ xwo2){
  int blk = blockIdx.x;
  int side = blk >> 9; int b = blk & 511;
  const ushort4* xw = (const ushort4*)(side? xwi2:xwi1);
  const int* cur = side? cur2:cur1;
  const int* es  = side? es2:es1;
  float* ec = side? ec2:ec1;
  const float* deg = side? d2:d1;
  bf16t* h = side? h2:h1;
  int t = threadIdx.x;
  int c4 = t & 31;
  float4 bv = ((const float4*)bias)[c4];
  #pragma unroll
  for (int grp=0; grp<2; grp++){
    int i = b*16 + grp*8 + (t>>5);
    float dgi = deg[i];
    float sc = 1.0f/dgi;
    float rsq_d = rsqrtf(dgi);
    ushort4 v = xw[(size_t)i*32 + c4];
    float4 acc = {b2f(v.x)*sc, b2f(v.y)*sc, b2f(v.z)*sc, b2f(v.w)*sc};
    int r = i*MAXDEG;
    int ce = cur[i]; if (ce > MAXDEG) ce = MAXDEG;
    int r1 = r + ce;
    for (; r+3<r1; r+=4){
      int s0=es[r], s1=es[r+1], s2=es[r+2], s3=es[r+3];
      float w0=ec[r], w1=ec[r+1], w2=ec[r+2], w3=ec[r+3];
      if (coefmode){
        w0 *= rsqrtf(deg[s0])*rsq_d;
        w1 *= rsqrtf(deg[s1])*rsq_d;
        w2 *= rsqrtf(deg[s2])*rsq_d;
        w3 *= rsqrtf(deg[s3])*rsq_d;
        if (c4==0){ ec[r]=w0; ec[r+1]=w1; ec[r+2]=w2; ec[r+3]=w3; }
      }
      ushort4 u0 = xw[(size_t)s0*32 + c4];
      ushort4 u1 = xw[(size_t)s1*32 + c4];
      ushort4 u2 = xw[(size_t)s2*32 + c4];
      ushort4 u3 = xw[(size_t)s3*32 + c4];
      acc.x += b2f(u0.x)*w0 + b2f(u1.x)*w1 + b2f(u2.x)*w2 + b2f(u3.x)*w3;
      acc.y += b2f(u0.y)*w0 + b2f(u1.y)*w1 + b2f(u2.y)*w2 + b2f(u3.y)*w3;
      acc.z += b2f(u0.z)*w0 + b2f(u1.z)*w1 + b2f(u2.z)*w2 + b2f(u3.z)*w3;
      acc.w += b2f(u0.w)*w0 + b2f(u1.w)*w1 + b2f(u2.w)*w2 + b2f(u3.w)*w3;
    }
    for (; r<r1; r++){
      int s0=es[r]; float w0=ec[r];
      if (coefmode){
        w0 *= rsqrtf(deg[s0])*rsq_d;
        if (c4==0) ec[r]=w0;
      }
      ushort4 u0 = xw[(size_t)s0*32 + c4];
      acc.x+=b2f(u0.x)*w0; acc.y+=b2f(u0.y)*w0; acc.z+=b2f(u0.z)*w0; acc.w+=b2f(u0.w)*w0;
    }
    acc.x+=bv.x; acc.y+=bv.y; acc.z+=bv.z; acc.w+=bv.w;
    acc.x = (acc.x>0.f)?acc.x:0.2f*acc.x;
    acc.y = (acc.y>0.f)?acc.y:0.2f*acc.y;
    acc.z = (acc.z>0.f)?acc.z:0.2f*acc.z;
    acc.w = (acc.w>0.f)?acc.w:0.2f*acc.w;
    ((ushort4*)(h + (size_t)i*D3 + loff))[c4] =
      make_ushort4(f2bf(acc.x), f2bf(acc.y), f2bf(acc.z), f2bf(acc.w));
  }
  __syncthreads();
  // xw phase: same 16 rows, K=128 from the slice just written
  int w = t>>6, lane = t&63;
  int lm = lane&15, quad = lane>>4;
  const bf16t* x = (side? h2:h1) + loff;
  int r0 = b*16;
  int c0 = w*32;
  const bf16t* a = x + (size_t)(r0+lm)*D3 + quad*8;
  bf16t* xwo = side? xwo2:xwo1;
  f32x4 acc0={0,0,0,0}, acc1={0,0,0,0};
  for (int k=0;k<128;k+=32){
    short8v af = *(const short8v*)(a + k);
    short8v b0 = *(const short8v*)(Wl + (size_t)(c0+lm)*128 + quad*8 + k);
    short8v b1 = *(const short8v*)(Wl + (size_t)(c0+16+lm)*128 + quad*8 + k);
    acc0 = __builtin_amdgcn_mfma_f32_16x16x32_bf16(af, b0, acc0, 0,0,0);
    acc1 = __builtin_amdgcn_mfma_f32_16x16x32_bf16(af, b1, acc1, 0,0,0);
  }
  #pragma unroll
  for (int r=0;r<4;r++){
    int row = r0 + quad*4 + r;
    xwo[(size_t)row*NH + c0 + lm]      = f2bf(acc0[r]);
    xwo[(size_t)row*NH + c0 + 16 + lm] = f2bf(acc1[r]);
  }
}

// fused self-loop + bucket gather + bias + leaky; layer 2 fuses l2norm -> f bf16
__global__ __launch_bounds__(256) void k_gather(const bf16t* __restrict__ xw1, const bf16t* __restrict__ xw2,
                                                const int* __restrict__ cur1, const int* __restrict__ cur2,
                                                const int* __restrict__ es1, const int* __restrict__ es2,
                                                const float* __restrict__ ec1, const float* __restrict__ ec2,
                                                const float* __restrict__ d1, const float* __restrict__ d2,
                                                const float* __restrict__ b,
                                                bf16t* __restrict__ h1, bf16t* __restrict__ h2, int loff,
                                                int l2mode, bf16t* __restrict__ f1, bf16t* __restrict__ f2){
  int blk = blockIdx.x;
  int side = blk >> 10; int bb = blk & 1023;
  const ushort4* xw = (const ushort4*)(side? xw2:xw1);
  const int* cur = side? cur2:cur1;
  const int* es  = side? es2:es1;
  const float* ec= side? ec2:ec1;
  const float* deg = side? d2:d1;
  bf16t* h = side? h2:h1;
  int t = threadIdx.x;
  int i = bb*8 + (t>>5);
  int c4 = t & 31;
  float sc = 1.0f/deg[i];
  ushort4 v = xw[(size_t)i*32 + c4];
  float4 acc = {b2f(v.x)*sc, b2f(v.y)*sc, b2f(v.z)*sc, b2f(v.w)*sc};
  int r = i*MAXDEG;
  int ce = cur[i]; if (ce > MAXDEG) ce = MAXDEG;
  int r1 = r + ce;
  for (; r+3<r1; r+=4){
    int s0=es[r], s1=es[r+1], s2=es[r+2], s3=es[r+3];
    float w0=ec[r], w1=ec[r+1], w2=ec[r+2], w3=ec[r+3];
    ushort4 u0 = xw[(size_t)s0*32 + c4];
    ushort4 u1 = xw[(size_t)s1*32 + c4];
    ushort4 u2 = xw[(size_t)s2*32 + c4];
    ushort4 u3 = xw[(size_t)s3*32 + c4];
    acc.x += b2f(u0.x)*w0 + b2f(u1.x)*w1 + b2f(u2.x)*w2 + b2f(u3.x)*w3;
    acc.y += b2f(u0.y)*w0 + b2f(u1.y)*w1 + b2f(u2.y)*w2 + b2f(u3.y)*w3;
    acc.z += b2f(u0.z)*w0 + b2f(u1.z)*w1 + b2f(u2.z)*w2 + b2f(u3.z)*w3;
    acc.w += b2f(u0.w)*w0 + b2f(u1.w)*w1 + b2f(u2.w)*w2 + b2f(u3.w)*w3;
  }
  for (; r<r1; r++){
    int s0=es[r]; float w0=ec[r];
    ushort4 u0 = xw[(size_t)s0*32 + c4];
    acc.x+=b2f(u0.x)*w0; acc.y+=b2f(u0.y)*w0; acc.z+=b2f(u0.z)*w0; acc.w+=b2f(u0.w)*w0;
  }
  float4 bv = ((const float4*)b)[c4];
  acc.x+=bv.x; acc.y+=bv.y; acc.z+=bv.z; acc.w+=bv.w;
  acc.x = (acc.x>0.f)?acc.x:0.2f*acc.x;
  acc.y = (acc.y>0.f)?acc.y:0.2f*acc.y;
  acc.z = (acc.z>0.f)?acc.z:0.2f*acc.z;
  acc.w = (acc.w>0.f)?acc.w:0.2f*acc.w;
  if (!l2mode){
    ((ushort4*)(h + (size_t)i*D3 + loff))[c4] =
      make_ushort4(f2bf(acc.x), f2bf(acc.y), f2bf(acc.z), f2bf(acc.w));
  } else {
    ushort4 u0 = ((const ushort4*)(h + (size_t)i*D3))[c4];
    ushort4 u1 = ((const ushort4*)(h + (size_t)i*D3 + 128))[c4];
    float4 v0 = {b2f(u0.x), b2f(u0.y), b2f(u0.z), b2f(u0.w)};
    float4 v1 = {b2f(u1.x), b2f(u1.y), b2f(u1.z), b2f(u1.w)};
    float ss = v0.x*v0.x+v0.y*v0.y+v0.z*v0.z+v0.w*v0.w
             + v1.x*v1.x+v1.y*v1.y+v1.z*v1.z+v1.w*v1.w
             + acc.x*acc.x+acc.y*acc.y+acc.z*acc.z+acc.w*acc.w;
    #pragma unroll
    for (int m=1;m<32;m<<=1) ss += __shfl_xor(ss, m, 64);   // 32-lane node group
    float scale = 1.0f/fmaxf(sqrtf(ss), 1e-12f);
    bf16t* f = side? f2:f1;
    ((ushort4*)(f + (size_t)i*D6))[c4]       = make_ushort4(f2bf(v0.x*scale),f2bf(v0.y*scale),f2bf(v0.z*scale),f2bf(v0.w*scale));
    ((ushort4*)(f + (size_t)i*D6 + 128))[c4] = make_ushort4(f2bf(v1.x*scale),f2bf(v1.y*scale),f2bf(v1.z*scale),f2bf(v1.w*scale));
    ((ushort4*)(f + (size_t)i*D6 + 256))[c4] = make_ushort4(f2bf(acc.x*scale),f2bf(acc.y*scale),f2bf(acc.z*scale),f2bf(acc.w*scale));
  }
}

// ---------- interaction fused + step-1 attention tail + co-dispatched late-setup ----------
// blocks [0,512)     : per-(graph,side) S in LDS + apply + step-1 attention tail
// blocks [512,2816)  : Wih right half -> bf16 [3072][768]   (consumed by k_gates)
// blocks [2816,3584) : Wp1 fp32 -> bf16                     (consumed by p1)
// blocks [3584,4352) : cvec (4 waves/block, h0 in LDS)      (consumed by k_gates)
__global__ __launch_bounds__(256) void k_inter(bf16t* __restrict__ f1, bf16t* __restrict__ f2,
                                               const int* __restrict__ st1, const int* __restrict__ st2,
                                               const float* __restrict__ bih, const float* __restrict__ bhh,
                                               bf16t* __restrict__ Ab,
                                               const float* __restrict__ Wih, short* __restrict__ Wih16,
                                               const float* __restrict__ Wp1, short* __restrict__ Wp116,
                                               const float* __restrict__ Whh, float* __restrict__ cvec){
  __shared__ __align__(16) bf16t Sld[SMM*SLD];   // 19968 B; re-aliased by attention tail / cvec
  __shared__ bf16t tbuf[32*392];                  // 24.5 KB
  int bx = blockIdx.x;
  int t = threadIdx.x;
  if (bx >= 512){
    if (bx < 2816){
      int tt = (bx-512)*256 + t;
      int n = tt/192, q = tt - n*192;
      float4 v = ((const float4*)(Wih + (size_t)n*1536 + 768))[q];
      short4 o = { (short)f2bf(v.x), (short)f2bf(v.y), (short)f2bf(v.z), (short)f2bf(v.w) };
      ((short4*)Wih16)[tt] = o;
    } else if (bx < 3584){
      int tt = (bx-2816)*256 + t;
      float4 v = ((const float4*)Wp1)[tt];
      short4 o = { (short)f2bf(v.x), (short)f2bf(v.y), (short)f2bf(v.z), (short)f2bf(v.w) };
      ((short4*)Wp116)[tt] = o;
    } else {
      float* hs = (float*)Sld;
      int j0 = (bx - 3584)*4;
      for (int k=t; k<D6; k+=256) hs[k] = h0val(bih,bhh,k);
      __syncthreads();
      int w = t>>6, lane = t&63;
      int j = j0 + w;
      const float4* wi = (const float4*)(Wih + (size_t)j*(2*D6));
      const float4* wh = (const float4*)(Whh + (size_t)j*D6);
      const float4* h4 = (const float4*)hs;
      float acc=0;
      #pragma unroll
      for (int m=0;m<3;m++){
        float4 hv = h4[m*64+lane];
        float4 a = wi[m*64+lane];
        float4 bb = wh[m*64+lane];
        acc += hv.x*(a.x+bb.x) + hv.y*(a.y+bb.y) + hv.z*(a.z+bb.z) + hv.w*(a.w+bb.w);
      }
      #pragma unroll
      for (int m=1;m<64;m<<=1) acc += __shfl_xor(acc,m,64);
      if (lane==0) cvec[j]=acc+bih[j]+bhh[j];
    }
    return;
  }
  int side = bx >> 8, g = bx & (NB-1);
  int i0 = st1[g]; int n1 = st1[g+1]-i0; if (n1>SMM) n1=SMM;
  int j0 = st2[g]; int n2 = st2[g+1]-j0; if (n2>SMM) n2=SMM;
  int cnt = side? n2 : n1;
  int J   = side? n1 : n2;
  int r0base = side? j0 : i0;
  int c0base = side? i0 : j0;
  const bf16t* rowp = (side? f2 : f1);
  const bf16t* colp = (side? f1 : f2);
  const bf16t* src = colp + (size_t)c0base*D6;
  bf16t* dst = (side? f2 : f1) + (size_t)r0base*D6 + D3;
  int w = t>>6, lane = t&63;
  int lm = lane & 15, quad = lane >> 4;
  {
    uint4* z1 = (uint4*)Sld;
    uint4 zz = make_uint4(0,0,0,0);
    for (int i=t; i<1248; i+=256) z1[i]=zz;
  }
  __syncthreads();
  int nti = (cnt+15)>>4, ntj = (J+15)>>4;
  for (int tile = w; tile < nti*ntj; tile += 4){
    int ti = tile/ntj, tj = tile - ti*ntj;
    int ar = r0base + ti*16 + lm; if (ar > N_NODES-1) ar = N_NODES-1;
    int br = c0base + tj*16 + lm; if (br > N_NODES-1) br = N_NODES-1;
    const bf16t* a = rowp + (size_t)ar*D6 + quad*8;
    const bf16t* b = colp + (size_t)br*D6 + quad*8;
    f32x4 acc = {0,0,0,0};
    #pragma unroll
    for (int k=0; k<384; k+=32){
      short8v af = *(const short8v*)(a + k);
      short8v bf = *(const short8v*)(b + k);
      acc = __builtin_amdgcn_mfma_f32_16x16x32_bf16(af, bf, acc, 0, 0, 0);
    }
    int col = tj*16 + lm;
    #pragma unroll
    for (int r=0;r<4;r++){
      int row = ti*16 + quad*4 + r;
      if (row < cnt && col < J)
        Sld[row*SLD + col] = f2bf(acc[r]);
    }
  }
  __syncthreads();
  for (int r0=0; r0<cnt; r0+=32){
    int mt1 = (cnt - r0 > 16) ? 2 : 1;
    f32x4 acc[2][6] = {};
    for (int kb = 0; kb < J; kb += 32){
      __syncthreads();
      for (int idx = t; idx < 32*48; idx += 256){
        int j = idx/48, cg2 = idx - j*48;
        uint4 v = (kb+j < J)? ((const uint4*)(src + (size_t)(kb+j)*D6))[cg2] : make_uint4(0,0,0,0);
        *(uint4*)(tbuf + j*392 + cg2*8) = v;
      }
      const bf16t* ap = Sld + (r0 + lm)*SLD + kb + quad*8;
      short8v af0 = *(const short8v*)ap;
      short8v af1 = (mt1 > 1)? *(const short8v*)(ap + 16*SLD) : af0;
      __syncthreads();
      #pragma unroll
      for (int ni = 0; ni < 6; ni++){
        int nt = w*6 + ni;
        short8v bf;
        #pragma unroll
        for (int ji = 0; ji < 8; ji++)
          bf[ji] = (short)tbuf[(quad*8 + ji)*392 + nt*16 + lm];
        acc[0][ni] = __builtin_amdgcn_mfma_f32_16x16x32_bf16(af0, bf, acc[0][ni], 0, 0, 0);
        if (mt1 > 1)
          acc[1][ni] = __builtin_amdgcn_mfma_f32_16x16x32_bf16(af1, bf, acc[1][ni], 0, 0, 0);
      }
    }
    for (int mt = 0; mt < mt1; mt++)
      for (int ni = 0; ni < 6; ni++){
        int nt = w*6 + ni;
        #pragma unroll
        for (int r = 0; r < 4; r++){
          int row = r0 + mt*16 + quad*4 + r;
          if (row < cnt) dst[(size_t)row*D6 + nt*16 + lm] = f2bf(acc[mt][ni][r]);
        }
      }
  }
  // ---- step-1 attention tail for this (g,side); Sld re-aliased as hs/e_s/part ----
  __syncthreads();
  {
    float4* hs = (float4*)Sld;                 // 192 float4 = 3072 B
    float* e_s = ((float*)Sld) + 768;          // 96 floats
    float* part = ((float*)Sld) + 864;         // 4*768 floats
    const bf16t* x = rowp + (size_t)r0base*D6;
    if (t<192){
      int j = t*4;
      hs[t] = make_float4(h0val(bih,bhh,j), h0val(bih,bhh,j+1), h0val(bih,bhh,j+2), h0val(bih,bhh,j+3));
    }
    __syncthreads();
    for (int n=w; n<cnt; n+=4){
      const uint2* xr = (const uint2*)(x + (size_t)n*D6);
      float p = 0;
      #pragma unroll
      for (int m=0;m<3;m++){
        uint2 rv = xr[m*64+lane];
        float4 hvv = hs[m*64+lane];
        p += bfl(rv.x)*hvv.x + bfh(rv.x)*hvv.y + bfl(rv.y)*hvv.z + bfh(rv.y)*hvv.w;
      }
      #pragma unroll
      for (int m=1;m<64;m<<=1) p += __shfl_xor(p,m,64);
      if (lane==0) e_s[n]=p;
    }
    __syncthreads();
    if (w==0){
      float mx=-INFINITY;
      for (int n=lane;n<cnt;n+=64) mx=fmaxf(mx,e_s[n]);
      #pragma unroll
      for (int m=1;m<64;m<<=1) mx=fmaxf(mx,__shfl_xor(mx,m,64));
      float s=0;
      for (int n=lane;n<cnt;n+=64) s+=__expf(e_s[n]-mx);
      #pragma unroll
      for (int m=1;m<64;m<<=1) s+=__shfl_xor(s,m,64);
      float inv=1.0f/s;
      for (int n=lane;n<cnt;n+=64) e_s[n]=__expf(e_s[n]-mx)*inv;
    }
    __syncthreads();
    float av[3][4] = {};
    for (int n=w; n<cnt; n+=4){
      float a = e_s[n];
      const uint2* xr = (const uint2*)(x + (size_t)n*D6);
      #pragma unroll
      for (int m=0;m<3;m++){
        uint2 rv = xr[m*64+lane];
        av[m][0]+=a*bfl(rv.x); av[m][1]+=a*bfh(rv.x); av[m][2]+=a*bfl(rv.y); av[m][3]+=a*bfh(rv.y);
      }
    }
    #pragma unroll
    for (int m=0;m<3;m++)
      *(float4*)&part[w*D6 + (m*64+lane)*4] = make_float4(av[m][0],av[m][1],av[m][2],av[m][3]);
    __syncthreads();
    if (t<192){
      float4 p0 = *(const float4*)&part[0*D6 + t*4];
      float4 p1 = *(const float4*)&part[1*D6 + t*4];
      float4 p2 = *(const float4*)&part[2*D6 + t*4];
      float4 p3 = *(const float4*)&part[3*D6 + t*4];
      float4 s = make_float4(p0.x+p1.x+p2.x+p3.x, p0.y+p1.y+p2.y+p3.y,
                             p0.z+p1.z+p2.z+p3.z, p0.w+p1.w+p2.w+p3.w);
      ushort4 o = make_ushort4(f2bf(s.x), f2bf(s.y), f2bf(s.z), f2bf(s.w));
      ((ushort4*)(Ab + (size_t)(side*NB+g)*D6))[t]=o;
    }
  }
}

// ---------- set2set ----------

// fused attention: e=x.hv, segment softmax, r=sum a*x (wave-parallel); x bf16; r bf16
__global__ __launch_bounds__(256) void k_att(const bf16t* __restrict__ f1, const bf16t* __restrict__ f2,
                                             const float* __restrict__ hbase, int perseg,
                                             const float* __restrict__ bih, const float* __restrict__ bhh,
                                             const int* __restrict__ st1, const int* __restrict__ st2,
                                             bf16t* __restrict__ dst16, long sidestep, long dstride){
  __shared__ float4 hs[192];
  __shared__ float e_s[SMM];
  __shared__ float part[4][D6];
  int side = blockIdx.x >> 8, g = blockIdx.x & (NB-1);
  const int* st = side? st2:st1;
  int n0 = st[g]; int cnt = st[g+1]-n0; if (cnt>SMM) cnt=SMM;
  const bf16t* x = (side? f2:f1) + (size_t)n0*D6;
  int t = threadIdx.x, w = t>>6, lane = t&63;
  if (t<192){
    if (perseg){
      hs[t] = ((const float4*)(hbase + (size_t)(side*NB+g)*D6))[t];
    } else {
      int j = t*4;
      hs[t] = make_float4(h0val(bih,bhh,j), h0val(bih,bhh,j+1), h0val(bih,bhh,j+2), h0val(bih,bhh,j+3));
    }
  }
  __syncthreads();
  for (int n=w; n<cnt; n+=4){
    const uint2* xr = (const uint2*)(x + (size_t)n*D6);
    float p = 0;
    #pragma unroll
    for (int m=0;m<3;m++){
      uint2 rv = xr[m*64+lane];
      float4 hvv = hs[m*64+lane];
      p += bfl(rv.x)*hvv.x + bfh(rv.x)*hvv.y + bfl(rv.y)*hvv.z + bfh(rv.y)*hvv.w;
    }
    #pragma unroll
    for (int m=1;m<64;m<<=1) p += __shfl_xor(p,m,64);
    if (lane==0) e_s[n]=p;
  }
  __syncthreads();
  if (w==0){
    float mx=-INFINITY;
    for (int n=lane;n<cnt;n+=64) mx=fmaxf(mx,e_s[n]);
    #pragma unroll
    for (int m=1;m<64;m<<=1) mx=fmaxf(mx,__shfl_xor(mx,m,64));
    float s=0;
    for (int n=lane;n<cnt;n+=64) s+=__expf(e_s[n]-mx);
    #pragma unroll
    for (int m=1;m<64;m<<=1) s+=__shfl_xor(s,m,64);
    float inv=1.0f/s;
    for (int n=lane;n<cnt;n+=64) e_s[n]=__expf(e_s[n]-mx)*inv;
  }
  __syncthreads();
  float av[3][4] = {};
  for (int n=w; n<cnt; n+=4){
    float a = e_s[n];
    const uint2* xr = (const uint2*)(x + (size_t)n*D6);
    #pragma unroll
    for (int m=0;m<3;m++){
      uint2 rv = xr[m*64+lane];
      av[m][0]+=a*bfl(rv.x); av[m][1]+=a*bfh(rv.x); av[m][2]+=a*bfl(rv.y); av[m][3]+=a*bfh(rv.y);
    }
  }
  #pragma unroll
  for (int m=0;m<3;m++)
    *(float4*)&part[w][(m*64+lane)*4] = make_float4(av[m][0],av[m][1],av[m][2],av[m][3]);
  __syncthreads();
  if (t<192){
    float4 p0 = *(const float4*)&part[0][t*4];
    float4 p1 = *(const float4*)&part[1][t*4];
    float4 p2 = *(const float4*)&part[2][t*4];
    float4 p3 = *(const float4*)&part[3][t*4];
    float4 s = make_float4(p0.x+p1.x+p2.x+p3.x, p0.y+p1.y+p2.y+p3.y,
                           p0.z+p1.z+p2.z+p3.z, p0.w+p1.w+p2.w+p3.w);
    ushort4 o = make_ushort4(f2bf(s.x), f2bf(s.y), f2bf(s.z), f2bf(s.w));
    ushort4* dp = (ushort4*)(dst16 + side*sidestep + (size_t)g*dstride);
    dp[t]=o;
  }
}

// fused gates GEMM + LSTM step-1 pointwise: wave w computes gate w for (16m x 64j) tile
__global__ __launch_bounds__(256) void k_gates(const short* __restrict__ A16,
                                               const short* __restrict__ B16,
                                               const float* __restrict__ cvec,
                                               const float* __restrict__ bih, const float* __restrict__ bhh,
                                               float* __restrict__ h1s, bf16t* __restrict__ z16){
  __shared__ float gbuf[4][16][66];
  int w = threadIdx.x >> 6, lane = threadIdx.x & 63;
  int lm = lane & 15, quad = lane >> 4;
  int bm = blockIdx.x * 16;
  int jb = blockIdx.y * 64;
  const short* a = A16 + (size_t)(bm + lm)*768 + quad*8;
  const short* b = B16 + (size_t)(w*768 + jb + lm)*768 + quad*8;
  f32x4 acc0={0,0,0,0}, acc1={0,0,0,0}, acc2={0,0,0,0}, acc3={0,0,0,0};
  for (int k=0; k<768; k+=32){
    short8v af = *(const short8v*)(a + k);
    short8v b0 = *(const short8v*)(b + k);
    short8v b1 = *(const short8v*)(b + 16*768 + k);
    short8v b2 = *(const short8v*)(b + 32*768 + k);
    short8v b3 = *(const short8v*)(b + 48*768 + k);
    acc0 = __builtin_amdgcn_mfma_f32_16x16x32_bf16(af, b0, acc0, 0, 0, 0);
    acc1 = __builtin_amdgcn_mfma_f32_16x16x32_bf16(af, b1, acc1, 0, 0, 0);
    acc2 = __builtin_amdgcn_mfma_f32_16x16x32_bf16(af, b2, acc2, 0, 0, 0);
    acc3 = __builtin_amdgcn_mfma_f32_16x16x32_bf16(af, b3, acc3, 0, 0, 0);
  }
  #pragma unroll
  for (int r=0;r<4;r++){
    gbuf[w][quad*4+r][lm]      = acc0[r];
    gbuf[w][quad*4+r][16+lm]   = acc1[r];
    gbuf[w][quad*4+r][32+lm]   = acc2[r];
    gbuf[w][quad*4+r][48+lm]   = acc3[r];
  }
  __syncthreads();
  int t = threadIdx.x;
  #pragma unroll
  for (int u=0; u<4; u++){
    int p = t + u*256;
    int mm = p>>6, jj = p&63;
    int j = jb + jj, m = bm + mm;
    float g4[4];
    #pragma unroll
    for (int q=0;q<4;q++) g4[q] = gbuf[q][mm][jj] + cvec[q*D6 + j];
    float c0j = sigf(bih[j]+bhh[j]) * tanhf(bih[2*D6+j]+bhh[2*D6+j]);
    float c = sigf(g4[1])*c0j + sigf(g4[0])*tanhf(g4[2]);
    float h = sigf(g4[3])*tanhf(c);
    h1s[(size_t)m*D6 + j] = h;
    int side = m>>8, g = m&255;
    z16[(size_t)g*3072 + side*1536 + j] = f2bf(h);
  }
}

// p1 GEMM via MFMA, split-K=16: pout[z][256x256]
__global__ __launch_bounds__(256) void k_gemm_mfma_p1(const short* __restrict__ A16,
                                                      const short* __restrict__ B16,
                                                      float* __restrict__ pout){
  int w = threadIdx.x >> 6, lane = threadIdx.x & 63;
  int lm = lane & 15, quad = lane >> 4;
  int bm = blockIdx.x * 16;
  int bn = w * 64;
  int kbase = blockIdx.y * 192;
  const short* a = A16 + (size_t)(bm + lm)*3072 + quad*8 + kbase;
  const short* b = B16 + (size_t)(bn + lm)*3072 + quad*8 + kbase;
  f32x4 acc0={0,0,0,0}, acc1={0,0,0,0}, acc2={0,0,0,0}, acc3={0,0,0,0};
  for (int k=0; k<192; k+=32){
    short8v af = *(const short8v*)(a + k);
    short8v b0 = *(const short8v*)(b + k);
    short8v b1 = *(const short8v*)(b + 16*3072 + k);
    short8v b2 = *(const short8v*)(b + 32*3072 + k);
    short8v b3 = *(const short8v*)(b + 48*3072 + k);
    acc0 = __builtin_amdgcn_mfma_f32_16x16x32_bf16(af, b0, acc0, 0, 0, 0);
    acc1 = __builtin_amdgcn_mfma_f32_16x16x32_bf16(af, b1, acc1, 0, 0, 0);
    acc2 = __builtin_amdgcn_mfma_f32_16x16x32_bf16(af, b2, acc2, 0, 0, 0);
    acc3 = __builtin_amdgcn_mfma_f32_16x16x32_bf16(af, b3, acc3, 0, 0, 0);
  }
  float* po = pout + (size_t)blockIdx.y*256*256;
  #pragma unroll
  for (int r=0;r<4;r++){
    size_t base = (size_t)(bm + quad*4 + r)*256 + bn + lm;
    po[base]      = acc0[r];
    po[base + 16] = acc1[r];
    po[base + 32] = acc2[r];
    po[base + 48] = acc3[r];
  }
}

// fused p1-reduce + p2 + p3: block per batch row
__global__ __launch_bounds__(128) void k_p23(const float* __restrict__ pbuf, const float* __restrict__ bp1,
                                             const float* __restrict__ Wp2, const float* __restrict__ bp2,
                                             const float* __restrict__ Wp3, const float* __restrict__ bp3,
                                             float* __restrict__ out){
  __shared__ float zr[256];
  __shared__ float ws[2];
  int m = blockIdx.x, t = threadIdx.x;
  float2 zacc = ((const float2*)(bp1))[t];
  #pragma unroll
  for (int p=0;p<16;p++){
    float2 v = ((const float2*)(pbuf + (size_t)p*256*256 + (size_t)m*256))[t];
    zacc.x += v.x; zacc.y += v.y;
  }
  zr[2*t]   = fmaxf(zacc.x, 0.f);
  zr[2*t+1] = fmaxf(zacc.y, 0.f);
  __syncthreads();
  const float4* wrow = (const float4*)(Wp2 + (size_t)t*256);
  const float4* z4 = (const float4*)zr;
  float acc = bp2[t];
  #pragma unroll 8
  for (int k=0;k<64;k++){
    float4 wv = wrow[k], zv = z4[k];
    acc += wv.x*zv.x + wv.y*zv.y + wv.z*zv.z + wv.w*zv.w;
  }
  float p = fmaxf(acc,0.f)*Wp3[t];
  #pragma unroll
  for (int o=32;o;o>>=1) p += __shfl_down(p,o,64);
  if ((t&63)==0) ws[t>>6]=p;
  __syncthreads();
  if (t==0){ float v=ws[0]+ws[1]+bp3[0]; out[m]=1.0f/(1.0f+__expf(-v)); }
}

// ---------- launch ----------

extern "C" void kernel_launch(void* const* d_in, const int* in_sizes, int n_in,
                              void* d_out, int out_size, void* d_ws, size_t ws_size,
                              hipStream_t stream){
  const float* feat1=(const float*)d_in[0];
  const float* feat2=(const float*)d_in[1];
  const float* ea1  =(const float*)d_in[2];
  const float* ea2  =(const float*)d_in[3];
  const float* W0=(const float*)d_in[4];  const float* b0=(const float*)d_in[5];
  const float* W1=(const float*)d_in[6];  const float* b1=(const float*)d_in[7];
  const float* W2=(const float*)d_in[8];  const float* b2=(const float*)d_in[9];
  const float* Wih=(const float*)d_in[10]; const float* bih=(const float*)d_in[11];
  const float* Whh=(const float*)d_in[12]; const float* bhh=(const float*)d_in[13];
  const float* Wp1=(const float*)d_in[14]; const float* bp1=(const float*)d_in[15];
  const float* Wp2=(const float*)d_in[16]; const float* bp2=(const float*)d_in[17];
  const float* Wp3=(const float*)d_in[18]; const float* bp3=(const float*)d_in[19];
  const int* ei1=(const int*)d_in[20]; const int* ei2=(const int*)d_in[21];
  const int* batch1=(const int*)d_in[22]; const int* batch2=(const int*)d_in[23];
  float* out = (float*)d_out;

  float* base = (float*)d_ws;
  size_t off = 0;
  auto alloc = [&](size_t n)->float* { float* r = base + off; off += (n + 255) & ~(size_t)255; return r; };
  float* deg1 = alloc(N_NODES);          float* deg2 = alloc(N_NODES);
  bf16t* xwA1 = (bf16t*)alloc((size_t)N_NODES*NH/2);
  bf16t* xwA2 = (bf16t*)alloc((size_t)N_NODES*NH/2);
  bf16t* xwB1 = (bf16t*)alloc((size_t)N_NODES*NH/2);
  bf16t* xwB2 = (bf16t*)alloc((size_t)N_NODES*NH/2);
  bf16t* hb1  = (bf16t*)alloc((size_t)N_NODES*D3/2);
  bf16t* hb2  = (bf16t*)alloc((size_t)N_NODES*D3/2);
  bf16t* xf1  = (bf16t*)alloc((size_t)N_NODES*64/2);
  bf16t* xf2  = (bf16t*)alloc((size_t)N_NODES*64/2);
  bf16t* Wtb  = (bf16t*)alloc((size_t)(128*64 + 2*128*128)/2);
  bf16t* f1   = (bf16t*)alloc((size_t)N_NODES*D6/2);
  bf16t* f2   = (bf16t*)alloc((size_t)N_NODES*D6/2);
  float* ecoef1 = alloc((size_t)N_NODES*MAXDEG);  float* ecoef2 = alloc((size_t)N_NODES*MAXDEG);
  float* cvec = alloc(4*D6);
  float* h1s  = alloc((size_t)512*D6);
  bf16t* zbuf16 = (bf16t*)alloc((size_t)256*3072/2);
  float* pbuf = alloc((size_t)16*256*256);
  short* Abuf16 = (short*)alloc((size_t)512*D6/2);
  short* Wih16  = (short*)alloc((size_t)3072*D6/2);
  short* Wp116  = (short*)alloc((size_t)256*3072/2);
  int* cnt1 = (int*)alloc(NB);   int* cnt2 = (int*)alloc(NB);
  int* st1  = (int*)alloc(NB+1); int* st2  = (int*)alloc(NB+1);
  int* ecur1= (int*)alloc(N_NODES); int* ecur2 = (int*)alloc(N_NODES);
  int* esrc1= (int*)alloc((size_t)N_NODES*MAXDEG); int* esrc2 = (int*)alloc((size_t)N_NODES*MAXDEG);
  (void)ws_size; (void)in_sizes; (void)n_in; (void)out_size;

  // minimal setup; bucket scatter||xw0; deg-from-buckets + scans
  k_setup  <<<1059,256,0,stream>>>(feat1,feat2,(short*)xf1,(short*)xf2,
                                   W0,W1,W2,Wtb, ecur1,ecur2,cnt1,cnt2);
  k_fill2  <<<1536,256,0,stream>>>(ei1,ea1, ei2,ea2,
                                   ecur1,esrc1,ecoef1, ecur2,esrc2,ecoef2,
                                   batch1,batch2,cnt1,cnt2,
                                   xf1,xf2,Wtb,xwA1,xwA2);
  k_deg2   <<<66,256,0,stream>>>(ecur1,ecoef1,deg1, ecur2,ecoef2,deg2,
                                 cnt1,cnt2,st1,st2);

  const bf16t* Wt1 = Wtb + 128*64;
  const bf16t* Wt2 = Wtb + 128*64 + 128*128;
  // gather0 (coef inline + write-back) + xw1
  k_gxw<<<1024,256,0,stream>>>(xwA1,xwA2, ecur1,ecur2, esrc1,esrc2, ecoef1,ecoef2,
                               deg1,deg2, b0, 0, 1, hb1,hb2, Wt1, xwB1,xwB2);
  // gather1 + xw2
  k_gxw<<<1024,256,0,stream>>>(xwB1,xwB2, ecur1,ecur2, esrc1,esrc2, ecoef1,ecoef2,
                               deg1,deg2, b1, NH, 0, hb1,hb2, Wt2, xwA1,xwA2);
  // gather2 (l2norm -> f)
  k_gather <<<2048,256,0,stream>>>(xwA1,xwA2,ecur1,ecur2,esrc1,esrc2,ecoef1,ecoef2,
                                   deg1,deg2,b2,hb1,hb2,2*NH,1,f1,f2);

  // fused interaction + step-1 attention tail || Wih16/Wp116 converts || cvec
  k_inter <<<4352,256,0,stream>>>(f1,f2,st1,st2,bih,bhh,(bf16t*)Abuf16,
                                  Wih,(short*)Wih16, Wp1,(short*)Wp116, Whh,cvec);

  // fused gates GEMM + LSTM step-1 pointwise
  k_gates<<<dim3(32,12),256,0,stream>>>(Abuf16, Wih16, cvec, bih, bhh, h1s, zbuf16);

  // step-2 attention (per-segment h) -> zbuf16 r-slots
  k_att<<<512,256,0,stream>>>(f1,f2,h1s,1,bih,bhh,st1,st2,
                              zbuf16+768,(long)1536,(long)3072);

  // MLP: p1 via MFMA (split-K=16); fused reduce+p2+p3
  k_gemm_mfma_p1<<<dim3(16,16),256,0,stream>>>((const short*)zbuf16, Wp116, pbuf);
  k_p23 <<<256,128,0,stream>>>(pbuf, bp1, Wp2, bp2, Wp3, bp3, out);
}

// Round 19
// 317.461 us; speedup vs baseline: 1.0847x; 1.0046x over previous
//
#include <hip/hip_runtime.h>
#include <cmath>

#define N_NODES 8192
#define N_EDGES 131072
#define NB      256
#define NH      128
#define D3      384
#define D6      768
#define SMM     96   // max nodes per (graph,side)
#define SLD     104  // LDS stride for S (96 + 8 pad)
#define MAXDEG  64   // bucket capacity per dst node; Binomial mean 16, 64 = +12 sigma

typedef __attribute__((ext_vector_type(8))) short short8v;
typedef __attribute__((ext_vector_type(4))) float f32x4;
typedef unsigned short bf16t;

__device__ __forceinline__ float sigf(float x){ return 1.0f/(1.0f+__expf(-x)); }
__device__ __forceinline__ unsigned short f2bf(float x){
  unsigned u = __float_as_uint(x);
  unsigned r = u + 0x7FFF + ((u>>16)&1);   // round-to-nearest-even
  return (unsigned short)(r>>16);
}
__device__ __forceinline__ float bfl(unsigned u){ return __uint_as_float(u<<16); }
__device__ __forceinline__ float bfh(unsigned u){ return __uint_as_float(u & 0xFFFF0000u); }
__device__ __forceinline__ float b2f(bf16t u){ return __uint_as_float(((unsigned)u)<<16); }
// h0[j] from LSTM step-0 collapse (q_star=h=c=0)
__device__ __forceinline__ float h0val(const float* bih, const float* bhh, int j){
  float c = sigf(bih[j]+bhh[j]) * tanhf(bih[2*D6+j]+bhh[2*D6+j]);
  return sigf(bih[3*D6+j]+bhh[3*D6+j]) * tanhf(c);
}

// xw = x @ W via MFMA (device body); x bf16 row stride xs, Wt bf16 [128][K]
// vb in [0,512): side*256+b; 4 waves = 32 rows x 128 cols
__device__ __forceinline__ void xw_body(int vb, int t,
    const bf16t* __restrict__ x1, const bf16t* __restrict__ x2, int xs, int K,
    const bf16t* __restrict__ Wt, bf16t* __restrict__ xw1, bf16t* __restrict__ xw2){
  int side = vb >> 8; int b = vb & 255;
  const bf16t* x = side? x2:x1;
  bf16t* xw = side? xw2:xw1;
  int w = t>>6, lane = t&63;
  int lm = lane&15, quad = lane>>4;
  int r0 = b*32 + (w>>1)*16;
  int c0 = (w&1)*64;
  const bf16t* a = x + (size_t)(r0+lm)*xs + quad*8;
  f32x4 acc[4] = {};
  for (int k=0;k<K;k+=32){
    short8v af = *(const short8v*)(a + k);
    #pragma unroll
    for (int ni=0;ni<4;ni++){
      short8v bf = *(const short8v*)(Wt + (size_t)(c0+ni*16+lm)*K + quad*8 + k);
      acc[ni] = __builtin_amdgcn_mfma_f32_16x16x32_bf16(af, bf, acc[ni], 0,0,0);
    }
  }
  #pragma unroll
  for (int ni=0;ni<4;ni++)
    #pragma unroll
    for (int r=0;r<4;r++){
      int row = r0 + quad*4 + r, col = c0 + ni*16 + lm;
      xw[(size_t)row*NH + col] = f2bf(acc[ni][r]);
    }
}

// ---------- setup ----------

// minimal critical-path setup, branch by block range:
//   [0,1024)     : feats fp32 -> bf16 (both sides)  [needed by k_fill2 xw0]
//   [1024,1027)  : W_l transpose -> bf16            [needed by k_fill2 xw0]
//   [1027,1059)  : init ecur/cnt                    [needed by k_fill2]
__global__ __launch_bounds__(256) void k_setup(
    const float* __restrict__ fe1, const float* __restrict__ fe2,
    short* __restrict__ xf1, short* __restrict__ xf2,
    const float* __restrict__ W0, const float* __restrict__ W1, const float* __restrict__ W2,
    bf16t* __restrict__ Wt,
    int* ecur1, int* ecur2, int* cnt1, int* cnt2){
  int b = blockIdx.x, tid = threadIdx.x;
  if (b < 1024){
    int t = b*256 + tid;
    int side = t >= 131072; int i = t & 131071;
    float4 v = ((const float4*)(side? fe2:fe1))[i];
    short4 o = { (short)f2bf(v.x), (short)f2bf(v.y), (short)f2bf(v.z), (short)f2bf(v.w) };
    ((short4*)(side? xf2:xf1))[i] = o;
  } else if (b < 1027){
    int l = b - 1024;
    const float* W = (l==0)? W0 : ((l==1)? W1 : W2);
    int K = (l==0)? 64 : 128;
    bf16t* dst = Wt + ((l==0)? 0 : ((l==1)? 128*64 : 128*64+128*128));
    for (int idx = tid; idx < 128*K; idx += 256){
      int n = idx / K, k = idx - n*K;
      dst[idx] = f2bf(W[k*NH + n]);
    }
  } else {
    int t = (b-1027)*256 + tid;
    if (t < N_NODES){ ecur1[t]=0; ecur2[t]=0; }
    if (t < NB){ cnt1[t]=0; cnt2[t]=0; }
  }
}

// bucket scatter + batch-cnt atomics (blocks 0-1023) || layer-0 xw MFMA (1024-1535)
// || Wih right-half convert (1536-3839) || Wp1 convert (3840-4607) || cvec (4608-5375)
// (converts/cvec depend only on kernel inputs; full occupancy here, no big LDS)
__global__ __launch_bounds__(256) void k_fill2(
    const int* __restrict__ ei1, const float* __restrict__ ea1,
    const int* __restrict__ ei2, const float* __restrict__ ea2,
    int* cur1, int* es1, float* ec1, int* cur2, int* es2, float* ec2,
    const int* __restrict__ b1, const int* __restrict__ b2, int* cnt1, int* cnt2,
    const bf16t* __restrict__ xf1, const bf16t* __restrict__ xf2,
    const bf16t* __restrict__ Wt, bf16t* __restrict__ xwA1, bf16t* __restrict__ xwA2,
    const float* __restrict__ Wih, short* __restrict__ Wih16,
    const float* __restrict__ Wp1, short* __restrict__ Wp116,
    const float* __restrict__ Whh, const float* __restrict__ bih, const float* __restrict__ bhh,
    float* __restrict__ cvec){
  __shared__ float hs[D6];
  int blk = blockIdx.x, tid = threadIdx.x;
  if (blk < 1024){
    int idx = blk*256 + tid;
    int side = idx >= N_EDGES;
    int e = idx & (N_EDGES-1);
    const int* ei = side? ei2:ei1; const float* ea = side? ea2:ea1;
    int* cur = side? cur2:cur1; int* es = side? es2:es1; float* ec = side? ec2:ec1;
    int s = ei[e], d = ei[N_EDGES+e];
    int pos = atomicAdd(&cur[d], 1);
    if (pos < MAXDEG){
      es[d*MAXDEG + pos] = s;
      ec[d*MAXDEG + pos] = ea[e];
    }
    if (idx < N_NODES){ atomicAdd(&cnt1[b1[idx]],1); atomicAdd(&cnt2[b2[idx]],1); }
  } else if (blk < 1536){
    xw_body(blk-1024, tid, xf1, xf2, 64, 64, Wt, xwA1, xwA2);
  } else if (blk < 3840){
    int tt = (blk-1536)*256 + tid;
    int n = tt/192, q = tt - n*192;
    float4 v = ((const float4*)(Wih + (size_t)n*1536 + 768))[q];
    short4 o = { (short)f2bf(v.x), (short)f2bf(v.y), (short)f2bf(v.z), (short)f2bf(v.w) };
    ((short4*)Wih16)[tt] = o;
  } else if (blk < 4608){
    int tt = (blk-3840)*256 + tid;
    float4 v = ((const float4*)Wp1)[tt];
    short4 o = { (short)f2bf(v.x), (short)f2bf(v.y), (short)f2bf(v.z), (short)f2bf(v.w) };
    ((short4*)Wp116)[tt] = o;
  } else {
    int j0 = (blk - 4608)*4;
    for (int k=tid; k<D6; k+=256) hs[k] = h0val(bih,bhh,k);
    __syncthreads();
    int w = tid>>6, lane = tid&63;
    int j = j0 + w;
    const float4* wi = (const float4*)(Wih + (size_t)j*(2*D6));
    const float4* wh = (const float4*)(Whh + (size_t)j*D6);
    const float4* h4 = (const float4*)hs;
    float acc=0;
    #pragma unroll
    for (int m=0;m<3;m++){
      float4 hv = h4[m*64+lane];
      float4 a = wi[m*64+lane];
      float4 bb = wh[m*64+lane];
      acc += hv.x*(a.x+bb.x) + hv.y*(a.y+bb.y) + hv.z*(a.z+bb.z) + hv.w*(a.w+bb.w);
    }
    #pragma unroll
    for (int m=1;m<64;m<<=1) acc += __shfl_xor(acc,m,64);
    if (lane==0) cvec[j]=acc+bih[j]+bhh[j];
  }
}

// deg from buckets (blocks 0-63: deg[i] = 1 + sum bucket ea, no atomics)
// + batch-count scans (blocks 64,65)
__global__ __launch_bounds__(256) void k_deg2(
    const int* __restrict__ cur1, const float* __restrict__ ec1, float* deg1,
    const int* __restrict__ cur2, const float* __restrict__ ec2, float* deg2,
    const int* __restrict__ c1, const int* __restrict__ c2, int* st1, int* st2){
  __shared__ int ps[256];
  int blk = blockIdx.x, t = threadIdx.x;
  if (blk < 64){
    int idx = blk*256 + t;
    int side = idx >= N_NODES;
    int i = idx & (N_NODES-1);
    const int* cur = side? cur2:cur1;
    const float* ec = side? ec2:ec1;
    float* deg = side? deg2:deg1;
    int ce = cur[i]; if (ce > MAXDEG) ce = MAXDEG;
    float s = 1.0f;
    const float* p = ec + (size_t)i*MAXDEG;
    for (int k=0;k<ce;k++) s += p[k];
    deg[i] = s;
  } else {
    const int* c = (blk==65)? c2:c1; int* st = (blk==65)? st2:st1;
    ps[t]=c[t]; __syncthreads();
    for (int d=1; d<256; d<<=1){
      int v = (t>=d)? ps[t-d]:0;
      __syncthreads();
      ps[t]+=v;
      __syncthreads();
    }
    st[t+1]=ps[t];
    if (t==0) st[0]=0;
  }
}

// ---------- GCN ----------

// fused gather(l) + xw(l+1), one block per (side, 16-row tile); grid 1024
// coefmode=1 (layer 0): ec holds raw ea; compute coef inline and write back
__global__ __launch_bounds__(256) void k_gxw(
    const bf16t* __restrict__ xwi1, const bf16t* __restrict__ xwi2,
    const int* __restrict__ cur1, const int* __restrict__ cur2,
    const int* __restrict__ es1, const int* __restrict__ es2,
    float* __restrict__ ec1, float* __restrict__ ec2,
    const float* __restrict__ d1, const float* __restrict__ d2,
    const float* __restrict__ bias, int loff, int coefmode,
    bf16t* __restrict__ h1, bf16t* __restrict__ h2,
    const bf16t* __restrict__ Wl,
    bf16t* __restrict__ xwo1, bf16t* __restrict__ xwo2){
  int blk = blockIdx.x;
  int side = blk >> 9; int b = blk & 511;
  const ushort4* xw = (const ushort4*)(side? xwi2:xwi1);
  const int* cur = side? cur2:cur1;
  const int* es  = side? es2:es1;
  float* ec = side? ec2:ec1;
  const float* deg = side? d2:d1;
  bf16t* h = side? h2:h1;
  int t = threadIdx.x;
  int c4 = t & 31;
  float4 bv = ((const float4*)bias)[c4];
  #pragma unroll
  for (int grp=0; grp<2; grp++){
    int i = b*16 + grp*8 + (t>>5);
    float dgi = deg[i];
    float sc = 1.0f/dgi;
    float rsq_d = rsqrtf(dgi);
    ushort4 v = xw[(size_t)i*32 + c4];
    float4 acc = {b2f(v.x)*sc, b2f(v.y)*sc, b2f(v.z)*sc, b2f(v.w)*sc};
    int r = i*MAXDEG;
    int ce = cur[i]; if (ce > MAXDEG) ce = MAXDEG;
    int r1 = r + ce;
    for (; r+3<r1; r+=4){
      int s0=es[r], s1=es[r+1], s2=es[r+2], s3=es[r+3];
      float w0=ec[r], w1=ec[r+1], w2=ec[r+2], w3=ec[r+3];
      if (coefmode){
        w0 *= rsqrtf(deg[s0])*rsq_d;
        w1 *= rsqrtf(deg[s1])*rsq_d;
        w2 *= rsqrtf(deg[s2])*rsq_d;
        w3 *= rsqrtf(deg[s3])*rsq_d;
        if (c4==0){ ec[r]=w0; ec[r+1]=w1; ec[r+2]=w2; ec[r+3]=w3; }
      }
      ushort4 u0 = xw[(size_t)s0*32 + c4];
      ushort4 u1 = xw[(size_t)s1*32 + c4];
      ushort4 u2 = xw[(size_t)s2*32 + c4];
      ushort4 u3 = xw[(size_t)s3*32 + c4];
      acc.x += b2f(u0.x)*w0 + b2f(u1.x)*w1 + b2f(u2.x)*w2 + b2f(u3.x)*w3;
      acc.y += b2f(u0.y)*w0 + b2f(u1.y)*w1 + b2f(u2.y)*w2 + b2f(u3.y)*w3;
      acc.z += b2f(u0.z)*w0 + b2f(u1.z)*w1 + b2f(u2.z)*w2 + b2f(u3.z)*w3;
      acc.w += b2f(u0.w)*w0 + b2f(u1.w)*w1 + b2f(u2.w)*w2 + b2f(u3.w)*w3;
    }
    for (; r<r1; r++){
      int s0=es[r]; float w0=ec[r];
      if (coefmode){
        w0 *= rsqrtf(deg[s0])*rsq_d;
        if (c4==0) ec[r]=w0;
      }
      ushort4 u0 = xw[(size_t)s0*32 + c4];
      acc.x+=b2f(u0.x)*w0; acc.y+=b2f(u0.y)*w0; acc.z+=b2f(u0.z)*w0; acc.w+=b2f(u0.w)*w0;
    }
    acc.x+=bv.x; acc.y+=bv.y; acc.z+=bv.z; acc.w+=bv.w;
    acc.x = (acc.x>0.f)?acc.x:0.2f*acc.x;
    acc.y = (acc.y>0.f)?acc.y:0.2f*acc.y;
    acc.z = (acc.z>0.f)?acc.z:0.2f*acc.z;
    acc.w = (acc.w>0.f)?acc.w:0.2f*acc.w;
    ((ushort4*)(h + (size_t)i*D3 + loff))[c4] =
      make_ushort4(f2bf(acc.x), f2bf(acc.y), f2bf(acc.z), f2bf(acc.w));
  }
  __syncthreads();
  // xw phase: same 16 rows, K=128 from the slice just written
  int w = t>>6, lane = t&63;
  int lm = lane&15, quad = lane>>4;
  const bf16t* x = (side? h2:h1) + loff;
  int r0 = b*16;
  int c0 = w*32;
  const bf16t* a = x + (size_t)(r0+lm)*D3 + quad*8;
  bf16t* xwo = side? xwo2:xwo1;
  f32x4 acc0={0,0,0,0}, acc1={0,0,0,0};
  for (int k=0;k<128;k+=32){
    short8v af = *(const short8v*)(a + k);
    short8v b0 = *(const short8v*)(Wl + (size_t)(c0+lm)*128 + quad*8 + k);
    short8v b1 = *(const short8v*)(Wl + (size_t)(c0+16+lm)*128 + quad*8 + k);
    acc0 = __builtin_amdgcn_mfma_f32_16x16x32_bf16(af, b0, acc0, 0,0,0);
    acc1 = __builtin_amdgcn_mfma_f32_16x16x32_bf16(af, b1, acc1, 0,0,0);
  }
  #pragma unroll
  for (int r=0;r<4;r++){
    int row = r0 + quad*4 + r;
    xwo[(size_t)row*NH + c0 + lm]      = f2bf(acc0[r]);
    xwo[(size_t)row*NH + c0 + 16 + lm] = f2bf(acc1[r]);
  }
}

// fused self-loop + bucket gather + bias + leaky; layer 2 fuses l2norm -> f bf16
__global__ __launch_bounds__(256) void k_gather(const bf16t* __restrict__ xw1, const bf16t* __restrict__ xw2,
                                                const int* __restrict__ cur1, const int* __restrict__ cur2,
                                                const int* __restrict__ es1, const int* __restrict__ es2,
                                                const float* __restrict__ ec1, const float* __restrict__ ec2,
                                                const float* __restrict__ d1, const float* __restrict__ d2,
                                                const float* __restrict__ b,
                                                bf16t* __restrict__ h1, bf16t* __restrict__ h2, int loff,
                                                int l2mode, bf16t* __restrict__ f1, bf16t* __restrict__ f2){
  int blk = blockIdx.x;
  int side = blk >> 10; int bb = blk & 1023;
  const ushort4* xw = (const ushort4*)(side? xw2:xw1);
  const int* cur = side? cur2:cur1;
  const int* es  = side? es2:es1;
  const float* ec= side? ec2:ec1;
  const float* deg = side? d2:d1;
  bf16t* h = side? h2:h1;
  int t = threadIdx.x;
  int i = bb*8 + (t>>5);
  int c4 = t & 31;
  float sc = 1.0f/deg[i];
  ushort4 v = xw[(size_t)i*32 + c4];
  float4 acc = {b2f(v.x)*sc, b2f(v.y)*sc, b2f(v.z)*sc, b2f(v.w)*sc};
  int r = i*MAXDEG;
  int ce = cur[i]; if (ce > MAXDEG) ce = MAXDEG;
  int r1 = r + ce;
  for (; r+3<r1; r+=4){
    int s0=es[r], s1=es[r+1], s2=es[r+2], s3=es[r+3];
    float w0=ec[r], w1=ec[r+1], w2=ec[r+2], w3=ec[r+3];
    ushort4 u0 = xw[(size_t)s0*32 + c4];
    ushort4 u1 = xw[(size_t)s1*32 + c4];
    ushort4 u2 = xw[(size_t)s2*32 + c4];
    ushort4 u3 = xw[(size_t)s3*32 + c4];
    acc.x += b2f(u0.x)*w0 + b2f(u1.x)*w1 + b2f(u2.x)*w2 + b2f(u3.x)*w3;
    acc.y += b2f(u0.y)*w0 + b2f(u1.y)*w1 + b2f(u2.y)*w2 + b2f(u3.y)*w3;
    acc.z += b2f(u0.z)*w0 + b2f(u1.z)*w1 + b2f(u2.z)*w2 + b2f(u3.z)*w3;
    acc.w += b2f(u0.w)*w0 + b2f(u1.w)*w1 + b2f(u2.w)*w2 + b2f(u3.w)*w3;
  }
  for (; r<r1; r++){
    int s0=es[r]; float w0=ec[r];
    ushort4 u0 = xw[(size_t)s0*32 + c4];
    acc.x+=b2f(u0.x)*w0; acc.y+=b2f(u0.y)*w0; acc.z+=b2f(u0.z)*w0; acc.w+=b2f(u0.w)*w0;
  }
  float4 bv = ((const float4*)b)[c4];
  acc.x+=bv.x; acc.y+=bv.y; acc.z+=bv.z; acc.w+=bv.w;
  acc.x = (acc.x>0.f)?acc.x:0.2f*acc.x;
  acc.y = (acc.y>0.f)?acc.y:0.2f*acc.y;
  acc.z = (acc.z>0.f)?acc.z:0.2f*acc.z;
  acc.w = (acc.w>0.f)?acc.w:0.2f*acc.w;
  if (!l2mode){
    ((ushort4*)(h + (size_t)i*D3 + loff))[c4] =
      make_ushort4(f2bf(acc.x), f2bf(acc.y), f2bf(acc.z), f2bf(acc.w));
  } else {
    ushort4 u0 = ((const ushort4*)(h + (size_t)i*D3))[c4];
    ushort4 u1 = ((const ushort4*)(h + (size_t)i*D3 + 128))[c4];
    float4 v0 = {b2f(u0.x), b2f(u0.y), b2f(u0.z), b2f(u0.w)};
    float4 v1 = {b2f(u1.x), b2f(u1.y), b2f(u1.z), b2f(u1.w)};
    float ss = v0.x*v0.x+v0.y*v0.y+v0.z*v0.z+v0.w*v0.w
             + v1.x*v1.x+v1.y*v1.y+v1.z*v1.z+v1.w*v1.w
             + acc.x*acc.x+acc.y*acc.y+acc.z*acc.z+acc.w*acc.w;
    #pragma unroll
    for (int m=1;m<32;m<<=1) ss += __shfl_xor(ss, m, 64);   // 32-lane node group
    float scale = 1.0f/fmaxf(sqrtf(ss), 1e-12f);
    bf16t* f = side? f2:f1;
    ((ushort4*)(f + (size_t)i*D6))[c4]       = make_ushort4(f2bf(v0.x*scale),f2bf(v0.y*scale),f2bf(v0.z*scale),f2bf(v0.w*scale));
    ((ushort4*)(f + (size_t)i*D6 + 128))[c4] = make_ushort4(f2bf(v1.x*scale),f2bf(v1.y*scale),f2bf(v1.z*scale),f2bf(v1.w*scale));
    ((ushort4*)(f + (size_t)i*D6 + 256))[c4] = make_ushort4(f2bf(acc.x*scale),f2bf(acc.y*scale),f2bf(acc.z*scale),f2bf(acc.w*scale));
  }
}

// ---------- interaction fused + step-1 attention tail, one block per (graph,side) ----------
__global__ __launch_bounds__(256) void k_inter(bf16t* __restrict__ f1, bf16t* __restrict__ f2,
                                               const int* __restrict__ st1, const int* __restrict__ st2,
                                               const float* __restrict__ bih, const float* __restrict__ bhh,
                                               bf16t* __restrict__ Ab){
  __shared__ __align__(16) bf16t Sld[SMM*SLD];   // 19968 B; re-aliased by attention tail
  __shared__ bf16t tbuf[32*392];                  // 24.5 KB
  int bx = blockIdx.x;
  int t = threadIdx.x;
  int side = bx >> 8, g = bx & (NB-1);
  int i0 = st1[g]; int n1 = st1[g+1]-i0; if (n1>SMM) n1=SMM;
  int j0 = st2[g]; int n2 = st2[g+1]-j0; if (n2>SMM) n2=SMM;
  int cnt = side? n2 : n1;
  int J   = side? n1 : n2;
  int r0base = side? j0 : i0;
  int c0base = side? i0 : j0;
  const bf16t* rowp = (side? f2 : f1);
  const bf16t* colp = (side? f1 : f2);
  const bf16t* src = colp + (size_t)c0base*D6;
  bf16t* dst = (side? f2 : f1) + (size_t)r0base*D6 + D3;
  int w = t>>6, lane = t&63;
  int lm = lane & 15, quad = lane >> 4;
  {
    uint4* z1 = (uint4*)Sld;
    uint4 zz = make_uint4(0,0,0,0);
    for (int i=t; i<1248; i+=256) z1[i]=zz;
  }
  __syncthreads();
  int nti = (cnt+15)>>4, ntj = (J+15)>>4;
  for (int tile = w; tile < nti*ntj; tile += 4){
    int ti = tile/ntj, tj = tile - ti*ntj;
    int ar = r0base + ti*16 + lm; if (ar > N_NODES-1) ar = N_NODES-1;
    int br = c0base + tj*16 + lm; if (br > N_NODES-1) br = N_NODES-1;
    const bf16t* a = rowp + (size_t)ar*D6 + quad*8;
    const bf16t* b = colp + (size_t)br*D6 + quad*8;
    f32x4 acc = {0,0,0,0};
    #pragma unroll
    for (int k=0; k<384; k+=32){
      short8v af = *(const short8v*)(a + k);
      short8v bf = *(const short8v*)(b + k);
      acc = __builtin_amdgcn_mfma_f32_16x16x32_bf16(af, bf, acc, 0, 0, 0);
    }
    int col = tj*16 + lm;
    #pragma unroll
    for (int r=0;r<4;r++){
      int row = ti*16 + quad*4 + r;
      if (row < cnt && col < J)
        Sld[row*SLD + col] = f2bf(acc[r]);
    }
  }
  __syncthreads();
  for (int r0=0; r0<cnt; r0+=32){
    int mt1 = (cnt - r0 > 16) ? 2 : 1;
    f32x4 acc[2][6] = {};
    for (int kb = 0; kb < J; kb += 32){
      __syncthreads();
      for (int idx = t; idx < 32*48; idx += 256){
        int j = idx/48, cg2 = idx - j*48;
        uint4 v = (kb+j < J)? ((const uint4*)(src + (size_t)(kb+j)*D6))[cg2] : make_uint4(0,0,0,0);
        *(uint4*)(tbuf + j*392 + cg2*8) = v;
      }
      const bf16t* ap = Sld + (r0 + lm)*SLD + kb + quad*8;
      short8v af0 = *(const short8v*)ap;
      short8v af1 = (mt1 > 1)? *(const short8v*)(ap + 16*SLD) : af0;
      __syncthreads();
      #pragma unroll
      for (int ni = 0; ni < 6; ni++){
        int nt = w*6 + ni;
        short8v bf;
        #pragma unroll
        for (int ji = 0; ji < 8; ji++)
          bf[ji] = (short)tbuf[(quad*8 + ji)*392 + nt*16 + lm];
        acc[0][ni] = __builtin_amdgcn_mfma_f32_16x16x32_bf16(af0, bf, acc[0][ni], 0, 0, 0);
        if (mt1 > 1)
          acc[1][ni] = __builtin_amdgcn_mfma_f32_16x16x32_bf16(af1, bf, acc[1][ni], 0, 0, 0);
      }
    }
    for (int mt = 0; mt < mt1; mt++)
      for (int ni = 0; ni < 6; ni++){
        int nt = w*6 + ni;
        #pragma unroll
        for (int r = 0; r < 4; r++){
          int row = r0 + mt*16 + quad*4 + r;
          if (row < cnt) dst[(size_t)row*D6 + nt*16 + lm] = f2bf(acc[mt][ni][r]);
        }
      }
  }
  // ---- step-1 attention tail for this (g,side); Sld re-aliased as hs/e_s/part ----
  __syncthreads();
  {
    float4* hs = (float4*)Sld;                 // 192 float4 = 3072 B
    float* e_s = ((float*)Sld) + 768;          // 96 floats
    float* part = ((float*)Sld) + 864;         // 4*768 floats
    const bf16t* x = rowp + (size_t)r0base*D6;
    if (t<192){
      int j = t*4;
      hs[t] = make_float4(h0val(bih,bhh,j), h0val(bih,bhh,j+1), h0val(bih,bhh,j+2), h0val(bih,bhh,j+3));
    }
    __syncthreads();
    for (int n=w; n<cnt; n+=4){
      const uint2* xr = (const uint2*)(x + (size_t)n*D6);
      float p = 0;
      #pragma unroll
      for (int m=0;m<3;m++){
        uint2 rv = xr[m*64+lane];
        float4 hvv = hs[m*64+lane];
        p += bfl(rv.x)*hvv.x + bfh(rv.x)*hvv.y + bfl(rv.y)*hvv.z + bfh(rv.y)*hvv.w;
      }
      #pragma unroll
      for (int m=1;m<64;m<<=1) p += __shfl_xor(p,m,64);
      if (lane==0) e_s[n]=p;
    }
    __syncthreads();
    if (w==0){
      float mx=-INFINITY;
      for (int n=lane;n<cnt;n+=64) mx=fmaxf(mx,e_s[n]);
      #pragma unroll
      for (int m=1;m<64;m<<=1) mx=fmaxf(mx,__shfl_xor(mx,m,64));
      float s=0;
      for (int n=lane;n<cnt;n+=64) s+=__expf(e_s[n]-mx);
      #pragma unroll
      for (int m=1;m<64;m<<=1) s+=__shfl_xor(s,m,64);
      float inv=1.0f/s;
      for (int n=lane;n<cnt;n+=64) e_s[n]=__expf(e_s[n]-mx)*inv;
    }
    __syncthreads();
    float av[3][4] = {};
    for (int n=w; n<cnt; n+=4){
      float a = e_s[n];
      const uint2* xr = (const uint2*)(x + (size_t)n*D6);
      #pragma unroll
      for (int m=0;m<3;m++){
        uint2 rv = xr[m*64+lane];
        av[m][0]+=a*bfl(rv.x); av[m][1]+=a*bfh(rv.x); av[m][2]+=a*bfl(rv.y); av[m][3]+=a*bfh(rv.y);
      }
    }
    #pragma unroll
    for (int m=0;m<3;m++)
      *(float4*)&part[w*D6 + (m*64+lane)*4] = make_float4(av[m][0],av[m][1],av[m][2],av[m][3]);
    __syncthreads();
    if (t<192){
      float4 p0 = *(const float4*)&part[0*D6 + t*4];
      float4 p1 = *(const float4*)&part[1*D6 + t*4];
      float4 p2 = *(const float4*)&part[2*D6 + t*4];
      float4 p3 = *(const float4*)&part[3*D6 + t*4];
      float4 s = make_float4(p0.x+p1.x+p2.x+p3.x, p0.y+p1.y+p2.y+p3.y,
                             p0.z+p1.z+p2.z+p3.z, p0.w+p1.w+p2.w+p3.w);
      ushort4 o = make_ushort4(f2bf(s.x), f2bf(s.y), f2bf(s.z), f2bf(s.w));
      ((ushort4*)(Ab + (size_t)(side*NB+g)*D6))[t]=o;
    }
  }
}

// ---------- set2set ----------

// fused attention: e=x.hv, segment softmax, r=sum a*x (wave-parallel); x bf16; r bf16
__global__ __launch_bounds__(256) void k_att(const bf16t* __restrict__ f1, const bf16t* __restrict__ f2,
                                             const float* __restrict__ hbase, int perseg,
                                             const float* __restrict__ bih, const float* __restrict__ bhh,
                                             const int* __restrict__ st1, const int* __restrict__ st2,
                                             bf16t* __restrict__ dst16, long sidestep, long dstride){
  __shared__ float4 hs[192];
  __shared__ float e_s[SMM];
  __shared__ float part[4][D6];
  int side = blockIdx.x >> 8, g = blockIdx.x & (NB-1);
  const int* st = side? st2:st1;
  int n0 = st[g]; int cnt = st[g+1]-n0; if (cnt>SMM) cnt=SMM;
  const bf16t* x = (side? f2:f1) + (size_t)n0*D6;
  int t = threadIdx.x, w = t>>6, lane = t&63;
  if (t<192){
    if (perseg){
      hs[t] = ((const float4*)(hbase + (size_t)(side*NB+g)*D6))[t];
    } else {
      int j = t*4;
      hs[t] = make_float4(h0val(bih,bhh,j), h0val(bih,bhh,j+1), h0val(bih,bhh,j+2), h0val(bih,bhh,j+3));
    }
  }
  __syncthreads();
  for (int n=w; n<cnt; n+=4){
    const uint2* xr = (const uint2*)(x + (size_t)n*D6);
    float p = 0;
    #pragma unroll
    for (int m=0;m<3;m++){
      uint2 rv = xr[m*64+lane];
      float4 hvv = hs[m*64+lane];
      p += bfl(rv.x)*hvv.x + bfh(rv.x)*hvv.y + bfl(rv.y)*hvv.z + bfh(rv.y)*hvv.w;
    }
    #pragma unroll
    for (int m=1;m<64;m<<=1) p += __shfl_xor(p,m,64);
    if (lane==0) e_s[n]=p;
  }
  __syncthreads();
  if (w==0){
    float mx=-INFINITY;
    for (int n=lane;n<cnt;n+=64) mx=fmaxf(mx,e_s[n]);
    #pragma unroll
    for (int m=1;m<64;m<<=1) mx=fmaxf(mx,__shfl_xor(mx,m,64));
    float s=0;
    for (int n=lane;n<cnt;n+=64) s+=__expf(e_s[n]-mx);
    #pragma unroll
    for (int m=1;m<64;m<<=1) s+=__shfl_xor(s,m,64);
    float inv=1.0f/s;
    for (int n=lane;n<cnt;n+=64) e_s[n]=__expf(e_s[n]-mx)*inv;
  }
  __syncthreads();
  float av[3][4] = {};
  for (int n=w; n<cnt; n+=4){
    float a = e_s[n];
    const uint2* xr = (const uint2*)(x + (size_t)n*D6);
    #pragma unroll
    for (int m=0;m<3;m++){
      uint2 rv = xr[m*64+lane];
      av[m][0]+=a*bfl(rv.x); av[m][1]+=a*bfh(rv.x); av[m][2]+=a*bfl(rv.y); av[m][3]+=a*bfh(rv.y);
    }
  }
  #pragma unroll
  for (int m=0;m<3;m++)
    *(float4*)&part[w][(m*64+lane)*4] = make_float4(av[m][0],av[m][1],av[m][2],av[m][3]);
  __syncthreads();
  if (t<192){
    float4 p0 = *(const float4*)&part[0][t*4];
    float4 p1 = *(const float4*)&part[1][t*4];
    float4 p2 = *(const float4*)&part[2][t*4];
    float4 p3 = *(const float4*)&part[3][t*4];
    float4 s = make_float4(p0.x+p1.x+p2.x+p3.x, p0.y+p1.y+p2.y+p3.y,
                           p0.z+p1.z+p2.z+p3.z, p0.w+p1.w+p2.w+p3.w);
    ushort4 o = make_ushort4(f2bf(s.x), f2bf(s.y), f2bf(s.z), f2bf(s.w));
    ushort4* dp = (ushort4*)(dst16 + side*sidestep + (size_t)g*dstride);
    dp[t]=o;
  }
}

// fused gates GEMM + LSTM step-1 pointwise: wave w computes gate w for (16m x 64j) tile
__global__ __launch_bounds__(256) void k_gates(const short* __restrict__ A16,
                                               const short* __restrict__ B16,
                                               const float* __restrict__ cvec,
                                               const float* __restrict__ bih, const float* __restrict__ bhh,
                                               float* __restrict__ h1s, bf16t* __restrict__ z16){
  __shared__ float gbuf[4][16][66];
  int w = threadIdx.x >> 6, lane = threadIdx.x & 63;
  int lm = lane & 15, quad = lane >> 4;
  int bm = blockIdx.x * 16;
  int jb = blockIdx.y * 64;
  const short* a = A16 + (size_t)(bm + lm)*768 + quad*8;
  const short* b = B16 + (size_t)(w*768 + jb + lm)*768 + quad*8;
  f32x4 acc0={0,0,0,0}, acc1={0,0,0,0}, acc2={0,0,0,0}, acc3={0,0,0,0};
  for (int k=0; k<768; k+=32){
    short8v af = *(const short8v*)(a + k);
    short8v b0 = *(const short8v*)(b + k);
    short8v b1 = *(const short8v*)(b + 16*768 + k);
    short8v b2 = *(const short8v*)(b + 32*768 + k);
    short8v b3 = *(const short8v*)(b + 48*768 + k);
    acc0 = __builtin_amdgcn_mfma_f32_16x16x32_bf16(af, b0, acc0, 0, 0, 0);
    acc1 = __builtin_amdgcn_mfma_f32_16x16x32_bf16(af, b1, acc1, 0, 0, 0);
    acc2 = __builtin_amdgcn_mfma_f32_16x16x32_bf16(af, b2, acc2, 0, 0, 0);
    acc3 = __builtin_amdgcn_mfma_f32_16x16x32_bf16(af, b3, acc3, 0, 0, 0);
  }
  #pragma unroll
  for (int r=0;r<4;r++){
    gbuf[w][quad*4+r][lm]      = acc0[r];
    gbuf[w][quad*4+r][16+lm]   = acc1[r];
    gbuf[w][quad*4+r][32+lm]   = acc2[r];
    gbuf[w][quad*4+r][48+lm]   = acc3[r];
  }
  __syncthreads();
  int t = threadIdx.x;
  #pragma unroll
  for (int u=0; u<4; u++){
    int p = t + u*256;
    int mm = p>>6, jj = p&63;
    int j = jb + jj, m = bm + mm;
    float g4[4];
    #pragma unroll
    for (int q=0;q<4;q++) g4[q] = gbuf[q][mm][jj] + cvec[q*D6 + j];
    float c0j = sigf(bih[j]+bhh[j]) * tanhf(bih[2*D6+j]+bhh[2*D6+j]);
    float c = sigf(g4[1])*c0j + sigf(g4[0])*tanhf(g4[2]);
    float h = sigf(g4[3])*tanhf(c);
    h1s[(size_t)m*D6 + j] = h;
    int side = m>>8, g = m&255;
    z16[(size_t)g*3072 + side*1536 + j] = f2bf(h);
  }
}

// p1 GEMM via MFMA, split-K=16: pout[z][256x256]
__global__ __launch_bounds__(256) void k_gemm_mfma_p1(const short* __restrict__ A16,
                                                      const short* __restrict__ B16,
                                                      float* __restrict__ pout){
  int w = threadIdx.x >> 6, lane = threadIdx.x & 63;
  int lm = lane & 15, quad = lane >> 4;
  int bm = blockIdx.x * 16;
  int bn = w * 64;
  int kbase = blockIdx.y * 192;
  const short* a = A16 + (size_t)(bm + lm)*3072 + quad*8 + kbase;
  const short* b = B16 + (size_t)(bn + lm)*3072 + quad*8 + kbase;
  f32x4 acc0={0,0,0,0}, acc1={0,0,0,0}, acc2={0,0,0,0}, acc3={0,0,0,0};
  for (int k=0; k<192; k+=32){
    short8v af = *(const short8v*)(a + k);
    short8v b0 = *(const short8v*)(b + k);
    short8v b1 = *(const short8v*)(b + 16*3072 + k);
    short8v b2 = *(const short8v*)(b + 32*3072 + k);
    short8v b3 = *(const short8v*)(b + 48*3072 + k);
    acc0 = __builtin_amdgcn_mfma_f32_16x16x32_bf16(af, b0, acc0, 0, 0, 0);
    acc1 = __builtin_amdgcn_mfma_f32_16x16x32_bf16(af, b1, acc1, 0, 0, 0);
    acc2 = __builtin_amdgcn_mfma_f32_16x16x32_bf16(af, b2, acc2, 0, 0, 0);
    acc3 = __builtin_amdgcn_mfma_f32_16x16x32_bf16(af, b3, acc3, 0, 0, 0);
  }
  float* po = pout + (size_t)blockIdx.y*256*256;
  #pragma unroll
  for (int r=0;r<4;r++){
    size_t base = (size_t)(bm + quad*4 + r)*256 + bn + lm;
    po[base]      = acc0[r];
    po[base + 16] = acc1[r];
    po[base + 32] = acc2[r];
    po[base + 48] = acc3[r];
  }
}

// fused p1-reduce + p2 + p3: block per batch row
__global__ __launch_bounds__(128) void k_p23(const float* __restrict__ pbuf, const float* __restrict__ bp1,
                                             const float* __restrict__ Wp2, const float* __restrict__ bp2,
                                             const float* __restrict__ Wp3, const float* __restrict__ bp3,
                                             float* __restrict__ out){
  __shared__ float zr[256];
  __shared__ float ws[2];
  int m = blockIdx.x, t = threadIdx.x;
  float2 zacc = ((const float2*)(bp1))[t];
  #pragma unroll
  for (int p=0;p<16;p++){
    float2 v = ((const float2*)(pbuf + (size_t)p*256*256 + (size_t)m*256))[t];
    zacc.x += v.x; zacc.y += v.y;
  }
  zr[2*t]   = fmaxf(zacc.x, 0.f);
  zr[2*t+1] = fmaxf(zacc.y, 0.f);
  __syncthreads();
  const float4* wrow = (const float4*)(Wp2 + (size_t)t*256);
  const float4* z4 = (const float4*)zr;
  float acc = bp2[t];
  #pragma unroll 8
  for (int k=0;k<64;k++){
    float4 wv = wrow[k], zv = z4[k];
    acc += wv.x*zv.x + wv.y*zv.y + wv.z*zv.z + wv.w*zv.w;
  }
  float p = fmaxf(acc,0.f)*Wp3[t];
  #pragma unroll
  for (int o=32;o;o>>=1) p += __shfl_down(p,o,64);
  if ((t&63)==0) ws[t>>6]=p;
  __syncthreads();
  if (t==0){ float v=ws[0]+ws[1]+bp3[0]; out[m]=1.0f/(1.0f+__expf(-v)); }
}

// ---------- launch ----------

extern "C" void kernel_launch(void* const* d_in, const int* in_sizes, int n_in,
                              void* d_out, int out_size, void* d_ws, size_t ws_size,
                              hipStream_t stream){
  const float* feat1=(const float*)d_in[0];
  const float* feat2=(const float*)d_in[1];
  const float* ea1  =(const float*)d_in[2];
  const float* ea2  =(const float*)d_in[3];
  const float* W0=(const float*)d_in[4];  const float* b0=(const float*)d_in[5];
  const float* W1=(const float*)d_in[6];  const float* b1=(const float*)d_in[7];
  const float* W2=(const float*)d_in[8];  const float* b2=(const float*)d_in[9];
  const float* Wih=(const float*)d_in[10]; const float* bih=(const float*)d_in[11];
  const float* Whh=(const float*)d_in[12]; const float* bhh=(const float*)d_in[13];
  const float* Wp1=(const float*)d_in[14]; const float* bp1=(const float*)d_in[15];
  const float* Wp2=(const float*)d_in[16]; const float* bp2=(const float*)d_in[17];
  const float* Wp3=(const float*)d_in[18]; const float* bp3=(const float*)d_in[19];
  const int* ei1=(const int*)d_in[20]; const int* ei2=(const int*)d_in[21];
  const int* batch1=(const int*)d_in[22]; const int* batch2=(const int*)d_in[23];
  float* out = (float*)d_out;

  float* base = (float*)d_ws;
  size_t off = 0;
  auto alloc = [&](size_t n)->float* { float* r = base + off; off += (n + 255) & ~(size_t)255; return r; };
  float* deg1 = alloc(N_NODES);          float* deg2 = alloc(N_NODES);
  bf16t* xwA1 = (bf16t*)alloc((size_t)N_NODES*NH/2);
  bf16t* xwA2 = (bf16t*)alloc((size_t)N_NODES*NH/2);
  bf16t* xwB1 = (bf16t*)alloc((size_t)N_NODES*NH/2);
  bf16t* xwB2 = (bf16t*)alloc((size_t)N_NODES*NH/2);
  bf16t* hb1  = (bf16t*)alloc((size_t)N_NODES*D3/2);
  bf16t* hb2  = (bf16t*)alloc((size_t)N_NODES*D3/2);
  bf16t* xf1  = (bf16t*)alloc((size_t)N_NODES*64/2);
  bf16t* xf2  = (bf16t*)alloc((size_t)N_NODES*64/2);
  bf16t* Wtb  = (bf16t*)alloc((size_t)(128*64 + 2*128*128)/2);
  bf16t* f1   = (bf16t*)alloc((size_t)N_NODES*D6/2);
  bf16t* f2   = (bf16t*)alloc((size_t)N_NODES*D6/2);
  float* ecoef1 = alloc((size_t)N_NODES*MAXDEG);  float* ecoef2 = alloc((size_t)N_NODES*MAXDEG);
  float* cvec = alloc(4*D6);
  float* h1s  = alloc((size_t)512*D6);
  bf16t* zbuf16 = (bf16t*)alloc((size_t)256*3072/2);
  float* pbuf = alloc((size_t)16*256*256);
  short* Abuf16 = (short*)alloc((size_t)512*D6/2);
  short* Wih16  = (short*)alloc((size_t)3072*D6/2);
  short* Wp116  = (short*)alloc((size_t)256*3072/2);
  int* cnt1 = (int*)alloc(NB);   int* cnt2 = (int*)alloc(NB);
  int* st1  = (int*)alloc(NB+1); int* st2  = (int*)alloc(NB+1);
  int* ecur1= (int*)alloc(N_NODES); int* ecur2 = (int*)alloc(N_NODES);
  int* esrc1= (int*)alloc((size_t)N_NODES*MAXDEG); int* esrc2 = (int*)alloc((size_t)N_NODES*MAXDEG);
  (void)ws_size; (void)in_sizes; (void)n_in; (void)out_size;

  // minimal setup; then scatter||xw0||converts||cvec (all input-only work up front)
  k_setup  <<<1059,256,0,stream>>>(feat1,feat2,(short*)xf1,(short*)xf2,
                                   W0,W1,W2,Wtb, ecur1,ecur2,cnt1,cnt2);
  k_fill2  <<<5376,256,0,stream>>>(ei1,ea1, ei2,ea2,
                                   ecur1,esrc1,ecoef1, ecur2,esrc2,ecoef2,
                                   batch1,batch2,cnt1,cnt2,
                                   xf1,xf2,Wtb,xwA1,xwA2,
                                   Wih,(short*)Wih16, Wp1,(short*)Wp116,
                                   Whh,bih,bhh,cvec);
  k_deg2   <<<66,256,0,stream>>>(ecur1,ecoef1,deg1, ecur2,ecoef2,deg2,
                                 cnt1,cnt2,st1,st2);

  const bf16t* Wt1 = Wtb + 128*64;
  const bf16t* Wt2 = Wtb + 128*64 + 128*128;
  // gather0 (coef inline + write-back) + xw1
  k_gxw<<<1024,256,0,stream>>>(xwA1,xwA2, ecur1,ecur2, esrc1,esrc2, ecoef1,ecoef2,
                               deg1,deg2, b0, 0, 1, hb1,hb2, Wt1, xwB1,xwB2);
  // gather1 + xw2
  k_gxw<<<1024,256,0,stream>>>(xwB1,xwB2, ecur1,ecur2, esrc1,esrc2, ecoef1,ecoef2,
                               deg1,deg2, b1, NH, 0, hb1,hb2, Wt2, xwA1,xwA2);
  // gather2 (l2norm -> f)
  k_gather <<<2048,256,0,stream>>>(xwA1,xwA2,ecur1,ecur2,esrc1,esrc2,ecoef1,ecoef2,
                                   deg1,deg2,b2,hb1,hb2,2*NH,1,f1,f2);

  // fused interaction: per-(graph,side) S in LDS + apply + step-1 attention tail
  k_inter <<<512,256,0,stream>>>(f1,f2,st1,st2,bih,bhh,(bf16t*)Abuf16);

  // fused gates GEMM + LSTM step-1 pointwise
  k_gates<<<dim3(32,12),256,0,stream>>>(Abuf16, Wih16, cvec, bih, bhh, h1s, zbuf16);

  // step-2 attention (per-segment h) -> zbuf16 r-slots
  k_att<<<512,256,0,stream>>>(f1,f2,h1s,1,bih,bhh,st1,st2,
                              zbuf16+768,(long)1536,(long)3072);

  // MLP: p1 via MFMA (split-K=16); fused reduce+p2+p3
  k_gemm_mfma_p1<<<dim3(16,16),256,0,stream>>>((const short*)zbuf16, Wp116, pbuf);
  k_p23 <<<256,128,0,stream>>>(pbuf, bp1, Wp2, bp2, Wp3, bp3, out);
}